// Round 2
// baseline (641.744 us; speedup 1.0000x reference)
//
#include <hip/hip_runtime.h>
#include <hip/hip_bf16.h>
#include <cstdint>

#define NN 1024
#define BBATCH 4
#define LLEN 12
#define DDIM 32
#define JW 384   // LLEN*DDIM
#define TIDC 288
#define DIWC 7

// Workspace budget (floats):
//  S 1048576 | rs 4096 | cs 4096 | U1 65536 | T1 18432 | D1 448 | X 1572864 | Z1 1572864 | Z2 1572864
//  total = 5,859,776 floats = 23,439,104 bytes (~22.4 MB)

// ---------------- K1: static support S = softmax(relu(emb_d @ emb_u^T), axis=1) ----------------
__global__ __launch_bounds__(256) void k_static(const float* __restrict__ emb_u,
                                                const float* __restrict__ emb_d,
                                                float* __restrict__ S) {
    int i = blockIdx.x;      // row
    int t = threadIdx.x;     // 256
    __shared__ float drow[32];
    __shared__ float red[256];
    if (t < 32) drow[t] = emb_d[i * 32 + t];
    __syncthreads();
    float v[4];
    float lsum = 0.f;
    for (int jj = 0; jj < 4; ++jj) {
        int j = jj * 256 + t;
        const float4* u4 = reinterpret_cast<const float4*>(emb_u + (size_t)j * 32);
        float acc = 0.f;
#pragma unroll
        for (int k4 = 0; k4 < 8; ++k4) {
            float4 u = u4[k4];
            acc += drow[k4 * 4 + 0] * u.x + drow[k4 * 4 + 1] * u.y +
                   drow[k4 * 4 + 2] * u.z + drow[k4 * 4 + 3] * u.w;
        }
        acc = fmaxf(acc, 0.f);
        v[jj] = __expf(acc);
        lsum += v[jj];
    }
    red[t] = lsum;
    __syncthreads();
    for (int s = 128; s > 0; s >>= 1) {
        if (t < s) red[t] += red[t + s];
        __syncthreads();
    }
    float inv = 1.f / red[0];
    for (int jj = 0; jj < 4; ++jj) S[(size_t)i * NN + jj * 256 + t] = v[jj] * inv;
}

// ---------------- K2a: raw row sums of adj ----------------
__global__ __launch_bounds__(256) void k_rowsum(const float* __restrict__ adj, float* __restrict__ rs) {
    int row = blockIdx.x;    // B*N
    const float* p = adj + (size_t)row * NN;
    int t = threadIdx.x;
    float s = p[t] + p[t + 256] + p[t + 512] + p[t + 768];
    __shared__ float red[256];
    red[t] = s;
    __syncthreads();
    for (int k = 128; k > 0; k >>= 1) {
        if (t < k) red[t] += red[t + k];
        __syncthreads();
    }
    if (t == 0) rs[row] = red[0];
}

// ---------------- K2b: raw col sums of adj (atomic partials; cs pre-zeroed) ----------------
__global__ __launch_bounds__(256) void k_colsum(const float* __restrict__ adj, float* __restrict__ cs) {
    int b = blockIdx.z;
    int j = blockIdx.x * 256 + threadIdx.x;
    int i0 = blockIdx.y * 64;
    const float* p = adj + ((size_t)b * NN + i0) * NN + j;
    float s = 0.f;
    for (int i = 0; i < 64; ++i) s += p[(size_t)i * NN];
    atomicAdd(&cs[b * NN + j], s);
}

// ---------------- K0: gate-MLP layer-1 tables ----------------
__global__ __launch_bounds__(64) void k_gate_pre(const float* __restrict__ emb_u,
                                                 const float* __restrict__ emb_d,
                                                 const float* __restrict__ W_g1,
                                                 const float* __restrict__ b_g1,
                                                 const float* __restrict__ TiD,
                                                 const float* __restrict__ DiW,
                                                 float* __restrict__ U1, float* __restrict__ T1,
                                                 float* __restrict__ D1) {
    int r = blockIdx.x;
    int h = threadIdx.x;   // 64
    if (r < NN) {
        float acc = b_g1[h];
        for (int i = 0; i < 32; ++i) acc = fmaf(emb_u[r * 32 + i], W_g1[(20 + i) * 64 + h], acc);
        for (int i = 0; i < 32; ++i) acc = fmaf(emb_d[r * 32 + i], W_g1[(52 + i) * 64 + h], acc);
        U1[r * 64 + h] = acc;
    } else if (r < NN + TIDC) {
        int tt = r - NN;
        float acc = 0.f;
        for (int i = 0; i < 10; ++i) acc = fmaf(TiD[tt * 10 + i], W_g1[i * 64 + h], acc);
        T1[tt * 64 + h] = acc;
    } else {
        int dd = r - (NN + TIDC);
        float acc = 0.f;
        for (int i = 0; i < 10; ++i) acc = fmaf(DiW[dd * 10 + i], W_g1[(10 + i) * 64 + h], acc);
        D1[dd * 64 + h] = acc;
    }
}

// ---------------- K3: fused H_st + H + gate + X_spa, output layout [b][n][l*32+d] ----------------
__global__ __launch_bounds__(256) void k_xspa(const float* __restrict__ hist,
                                              const float* __restrict__ hs,
                                              const float* __restrict__ W_emb,
                                              const float* __restrict__ b_emb,
                                              const float* __restrict__ W_st,
                                              const float* __restrict__ b_st,
                                              const float* __restrict__ U1,
                                              const float* __restrict__ T1,
                                              const float* __restrict__ D1,
                                              const float* __restrict__ W_g2,
                                              const float* __restrict__ b_g2,
                                              float* __restrict__ Xout) {
    __shared__ float Wst_sm[96 * 32];
    __shared__ float hs_sm[8][96];
    int t = threadIdx.x;
    for (int i = t; i < 96 * 32; i += 256) Wst_sm[i] = W_st[i];
    int ls = t >> 5, d = t & 31;
    int g = blockIdx.x * 8 + ls;                   // (b,n,l) with g = (b*N+n)*L + l
    int b = g / (NN * LLEN);
    int rem = g % (NN * LLEN);
    int n = rem / LLEN;
    int l = rem % LLEN;
    const float* hsp = hs + (size_t)g * 96;
    hs_sm[ls][d] = hsp[d];
    hs_sm[ls][d + 32] = hsp[d + 32];
    hs_sm[ls][d + 64] = hsp[d + 64];
    __syncthreads();
    float acc = b_st[d];
#pragma unroll 8
    for (int k = 0; k < 96; ++k) acc = fmaf(hs_sm[ls][k], Wst_sm[k * 32 + d], acc);
    size_t hidx = (((size_t)b * LLEN + l) * NN + n) * 3;
    float x0 = hist[hidx + 0];
    float x1 = hist[hidx + 1];
    float x2 = hist[hidx + 2] * (1.0f / 7.0f);
    int ti = (int)(x1 * 288.0f); ti = ti < 0 ? 0 : (ti > 287 ? 287 : ti);
    int di = (int)(x2 * 7.0f);   di = di < 0 ? 0 : (di > 6 ? 6 : di);
    float H = fmaxf(fmaf(x0, W_emb[d], b_emb[d]) + acc, 0.f);
    float g0 = U1[n * 64 + d] + T1[ti * 64 + d] + D1[di * 64 + d];
    float g1 = U1[n * 64 + 32 + d] + T1[ti * 64 + 32 + d] + D1[di * 64 + 32 + d];
    float gs = fmaxf(g0, 0.f) * W_g2[d] + fmaxf(g1, 0.f) * W_g2[32 + d];
#pragma unroll
    for (int m = 16; m >= 1; m >>= 1) gs += __shfl_xor(gs, m, 64);
    float gate = 1.f / (1.f + __expf(-(gs + b_g2[0])));
    Xout[((size_t)b * NN + n) * JW + l * 32 + d] = H * gate;
}

// ---------------- K4: one diffusion step for ONE support, 64x64 tile, BK=32, fp32 ----------------
// s=0: out = S @ In ; s=1: out[n,:] = (adj[n,:]@In + In[n,:]) / (rs[n]+1)
// s=2: out[n,:] = (adj[:,n]^T@In + In[n,:]) / (cs[n]+1)
__global__ __launch_bounds__(256) void k_diff1(const float* __restrict__ adj,
                                               const float* __restrict__ S,
                                               const float* __restrict__ rs,
                                               const float* __restrict__ cs,
                                               const float* __restrict__ In0,
                                               float* __restrict__ Out0,
                                               int s) {
    __shared__ float As[32][68];
    __shared__ float Bs[32][68];
    int b = blockIdx.z;
    int n0 = blockIdx.x * 64, j0 = blockIdx.y * 64;
    const float* In = In0 + (size_t)b * NN * JW;
    float* Out = Out0 + (size_t)b * NN * JW;
    const float* Ab = adj + (size_t)b * NN * NN;
    int t = threadIdx.x;
    int tx = t % 16, ty = t / 16;
    float acc[4][4] = {};
    for (int k0 = 0; k0 < NN; k0 += 32) {
        if (s == 2) {
            // As[k][n] = adj[b][k0+k][n0+n]  (direct rows)
#pragma unroll
            for (int p = 0; p < 2; ++p) {
                int k = t / 16 + p * 16;
                int c4 = (t % 16) * 4;
                float4 v = *reinterpret_cast<const float4*>(Ab + (size_t)(k0 + k) * NN + n0 + c4);
                *reinterpret_cast<float4*>(&As[k][c4]) = v;
            }
        } else {
            // As[k][n] = M[n0+n][k0+k] (transposed stage)
            const float* M = (s == 0) ? S : Ab;
#pragma unroll
            for (int p = 0; p < 2; ++p) {
                int n = t / 8 + p * 32;
                int k4 = (t % 8) * 4;
                float4 v = *reinterpret_cast<const float4*>(M + (size_t)(n0 + n) * NN + k0 + k4);
                As[k4 + 0][n] = v.x;
                As[k4 + 1][n] = v.y;
                As[k4 + 2][n] = v.z;
                As[k4 + 3][n] = v.w;
            }
        }
#pragma unroll
        for (int p = 0; p < 2; ++p) {
            int k = t / 16 + p * 16;
            int c4 = (t % 16) * 4;
            float4 v = *reinterpret_cast<const float4*>(In + (size_t)(k0 + k) * JW + j0 + c4);
            *reinterpret_cast<float4*>(&Bs[k][c4]) = v;
        }
        __syncthreads();
#pragma unroll 8
        for (int k = 0; k < 32; ++k) {
            float4 a = *reinterpret_cast<const float4*>(&As[k][ty * 4]);
            float4 bv = *reinterpret_cast<const float4*>(&Bs[k][tx * 4]);
            float av[4] = {a.x, a.y, a.z, a.w};
            float bb[4] = {bv.x, bv.y, bv.z, bv.w};
#pragma unroll
            for (int i = 0; i < 4; ++i)
#pragma unroll
                for (int j = 0; j < 4; ++j) acc[i][j] = fmaf(av[i], bb[j], acc[i][j]);
        }
        __syncthreads();
    }
#pragma unroll
    for (int i = 0; i < 4; ++i) {
        int n = n0 + ty * 4 + i;
        float scale = 1.f;
        if (s == 1) scale = 1.f / (rs[b * NN + n] + 1.f);
        else if (s == 2) scale = 1.f / (cs[b * NN + n] + 1.f);
        float4 v = make_float4(acc[i][0], acc[i][1], acc[i][2], acc[i][3]);
        if (s != 0) {
            float4 zv = *reinterpret_cast<const float4*>(In + (size_t)n * JW + j0 + tx * 4);
            v.x += zv.x; v.y += zv.y; v.z += zv.z; v.w += zv.w;
        }
        v.x *= scale; v.y *= scale; v.z *= scale; v.w *= scale;
        *reinterpret_cast<float4*>(Out + (size_t)n * JW + j0 + tx * 4) = v;
    }
}

// ---------------- K5a: out = b_dif + X @ W_dif[0:32] ----------------
__global__ __launch_bounds__(256) void k_out0(const float* __restrict__ X,
                                              const float* __restrict__ W_dif,
                                              const float* __restrict__ b_dif,
                                              float* __restrict__ out) {
    __shared__ float Wd[32 * 32];
    __shared__ float hc[8][32];
    int t = threadIdx.x;
    for (int i = t; i < 32 * 32; i += 256) Wd[i] = W_dif[i];
    int ls = t >> 5, d = t & 31;
    int g = blockIdx.x * 8 + ls;                  // (b,l,n) with g = (b*L+l)*N + n
    int b = g / (LLEN * NN);
    int rem = g % (LLEN * NN);
    int l = rem / NN;
    int n = rem % NN;
    size_t base = ((size_t)b * NN + n) * JW + l * 32 + d;
    hc[ls][d] = X[base];
    __syncthreads();
    float acc = b_dif[d];
#pragma unroll
    for (int k = 0; k < 32; ++k) acc = fmaf(hc[ls][k], Wd[k * 32 + d], acc);
    out[(size_t)g * 32 + d] = acc;
}

// ---------------- K5b: out += Z1 @ W_dif[row0:row0+32] + Z2 @ W_dif[row0+32:row0+64] ----------------
__global__ __launch_bounds__(256) void k_out_acc(const float* __restrict__ Z1,
                                                 const float* __restrict__ Z2,
                                                 const float* __restrict__ W_dif,
                                                 int row0,
                                                 float* __restrict__ out) {
    __shared__ float Wd[64 * 32];
    __shared__ float hc[8][64];
    int t = threadIdx.x;
    for (int i = t; i < 64 * 32; i += 256) Wd[i] = W_dif[(size_t)row0 * 32 + i];
    int ls = t >> 5, d = t & 31;
    int g = blockIdx.x * 8 + ls;                  // (b,l,n)
    int b = g / (LLEN * NN);
    int rem = g % (LLEN * NN);
    int l = rem / NN;
    int n = rem % NN;
    size_t base = ((size_t)b * NN + n) * JW + l * 32 + d;
    hc[ls][d] = Z1[base];
    hc[ls][32 + d] = Z2[base];
    __syncthreads();
    float acc = out[(size_t)g * 32 + d];
#pragma unroll
    for (int k = 0; k < 64; ++k) acc = fmaf(hc[ls][k], Wd[k * 32 + d], acc);
    out[(size_t)g * 32 + d] = acc;
}

extern "C" void kernel_launch(void* const* d_in, const int* in_sizes, int n_in,
                              void* d_out, int out_size, void* d_ws, size_t ws_size,
                              hipStream_t stream) {
    (void)in_sizes; (void)n_in; (void)out_size; (void)ws_size;
    const float* hist  = (const float*)d_in[0];
    const float* hs    = (const float*)d_in[1];
    const float* adj   = (const float*)d_in[2];
    const float* W_emb = (const float*)d_in[3];
    const float* b_emb = (const float*)d_in[4];
    const float* W_st  = (const float*)d_in[5];
    const float* b_st  = (const float*)d_in[6];
    const float* TiD   = (const float*)d_in[7];
    const float* DiW   = (const float*)d_in[8];
    const float* emb_u = (const float*)d_in[9];
    const float* emb_d = (const float*)d_in[10];
    const float* W_g1  = (const float*)d_in[11];
    const float* b_g1  = (const float*)d_in[12];
    const float* W_g2  = (const float*)d_in[13];
    const float* b_g2  = (const float*)d_in[14];
    const float* W_dif = (const float*)d_in[15];
    const float* b_dif = (const float*)d_in[16];
    float* out = (float*)d_out;

    float* ws = (float*)d_ws;
    float* S  = ws;                   // 1048576
    float* rs = S + 1048576;          // 4096
    float* cs = rs + 4096;            // 4096
    float* U1 = cs + 4096;            // 65536
    float* T1 = U1 + 65536;           // 18432
    float* D1 = T1 + 18432;           // 448
    float* X  = D1 + 448;             // 1572864
    float* Z1 = X + 1572864;          // 1572864
    float* Z2 = Z1 + 1572864;         // 1572864
    // total 5,859,776 floats = 23,439,104 bytes

    hipMemsetAsync(cs, 0, BBATCH * NN * sizeof(float), stream);
    k_static<<<NN, 256, 0, stream>>>(emb_u, emb_d, S);
    k_rowsum<<<BBATCH * NN, 256, 0, stream>>>(adj, rs);
    k_colsum<<<dim3(4, 16, 4), 256, 0, stream>>>(adj, cs);
    k_gate_pre<<<NN + TIDC + DIWC, 64, 0, stream>>>(emb_u, emb_d, W_g1, b_g1, TiD, DiW, U1, T1, D1);
    k_xspa<<<6144, 256, 0, stream>>>(hist, hs, W_emb, b_emb, W_st, b_st, U1, T1, D1, W_g2, b_g2, X);
    k_out0<<<6144, 256, 0, stream>>>(X, W_dif, b_dif, out);
    for (int c = 0; c < 3; ++c) {
        k_diff1<<<dim3(16, 6, 4), 256, 0, stream>>>(adj, S, rs, cs, X,  Z1, c);
        k_diff1<<<dim3(16, 6, 4), 256, 0, stream>>>(adj, S, rs, cs, Z1, Z2, c);
        k_out_acc<<<6144, 256, 0, stream>>>(Z1, Z2, W_dif, 32 + 64 * c, out);
    }
}

// Round 3
// 326.686 us; speedup vs baseline: 1.9644x; 1.9644x over previous
//
#include <hip/hip_runtime.h>
#include <hip/hip_bf16.h>
#include <cstdint>

#define NN 1024
#define BBATCH 4
#define LLEN 12
#define NJ 384   // LLEN*32
#define TIDC 288
#define DIWC 7

typedef __attribute__((ext_vector_type(8))) short short8;
typedef __attribute__((ext_vector_type(4))) float f32x4;

__device__ inline ushort f2bf(float f) {
    unsigned u = __float_as_uint(f);
    u += 0x7FFFu + ((u >> 16) & 1u);
    return (ushort)(u >> 16);
}
__device__ inline float bf2f(ushort u) { return __uint_as_float(((unsigned)u) << 16); }

// ---------------- K1: static support S = softmax(relu(emb_d @ emb_u^T), axis=1), bf16 out ----------------
__global__ __launch_bounds__(256) void k_static(const float* __restrict__ emb_u,
                                                const float* __restrict__ emb_d,
                                                ushort* __restrict__ S_bf) {
    int i = blockIdx.x;
    int t = threadIdx.x;
    __shared__ float drow[32];
    __shared__ float red[256];
    if (t < 32) drow[t] = emb_d[i * 32 + t];
    __syncthreads();
    float v[4];
    float lsum = 0.f;
    for (int jj = 0; jj < 4; ++jj) {
        int j = jj * 256 + t;
        const float4* u4 = reinterpret_cast<const float4*>(emb_u + (size_t)j * 32);
        float acc = 0.f;
#pragma unroll
        for (int k4 = 0; k4 < 8; ++k4) {
            float4 u = u4[k4];
            acc += drow[k4 * 4 + 0] * u.x + drow[k4 * 4 + 1] * u.y +
                   drow[k4 * 4 + 2] * u.z + drow[k4 * 4 + 3] * u.w;
        }
        acc = fmaxf(acc, 0.f);
        v[jj] = __expf(acc);
        lsum += v[jj];
    }
    red[t] = lsum;
    __syncthreads();
    for (int s = 128; s > 0; s >>= 1) {
        if (t < s) red[t] += red[t + s];
        __syncthreads();
    }
    float inv = 1.f / red[0];
    for (int jj = 0; jj < 4; ++jj) S_bf[(size_t)i * NN + jj * 256 + t] = f2bf(v[jj] * inv);
}

// ---------------- K2a: raw row sums of adj ----------------
__global__ __launch_bounds__(256) void k_rowsum(const float* __restrict__ adj, float* __restrict__ rs) {
    int row = blockIdx.x;    // B*N
    const float* p = adj + (size_t)row * NN;
    int t = threadIdx.x;
    float s = p[t] + p[t + 256] + p[t + 512] + p[t + 768];
    __shared__ float red[256];
    red[t] = s;
    __syncthreads();
    for (int k = 128; k > 0; k >>= 1) {
        if (t < k) red[t] += red[t + k];
        __syncthreads();
    }
    if (t == 0) rs[row] = red[0];
}

// ---------------- K2b: raw col sums of adj (atomic partials; cs pre-zeroed) ----------------
__global__ __launch_bounds__(256) void k_colsum(const float* __restrict__ adj, float* __restrict__ cs) {
    int b = blockIdx.z;
    int j = blockIdx.x * 256 + threadIdx.x;
    int i0 = blockIdx.y * 64;
    const float* p = adj + ((size_t)b * NN + i0) * NN + j;
    float s = 0.f;
    for (int i = 0; i < 64; ++i) s += p[(size_t)i * NN];
    atomicAdd(&cs[b * NN + j], s);
}

// ---------------- K0: gate-MLP layer-1 tables ----------------
__global__ __launch_bounds__(64) void k_gate_pre(const float* __restrict__ emb_u,
                                                 const float* __restrict__ emb_d,
                                                 const float* __restrict__ W_g1,
                                                 const float* __restrict__ b_g1,
                                                 const float* __restrict__ TiD,
                                                 const float* __restrict__ DiW,
                                                 float* __restrict__ U1, float* __restrict__ T1,
                                                 float* __restrict__ D1) {
    int r = blockIdx.x;
    int h = threadIdx.x;   // 64
    if (r < NN) {
        float acc = b_g1[h];
        for (int i = 0; i < 32; ++i) acc = fmaf(emb_u[r * 32 + i], W_g1[(20 + i) * 64 + h], acc);
        for (int i = 0; i < 32; ++i) acc = fmaf(emb_d[r * 32 + i], W_g1[(52 + i) * 64 + h], acc);
        U1[r * 64 + h] = acc;
    } else if (r < NN + TIDC) {
        int tt = r - NN;
        float acc = 0.f;
        for (int i = 0; i < 10; ++i) acc = fmaf(TiD[tt * 10 + i], W_g1[i * 64 + h], acc);
        T1[tt * 64 + h] = acc;
    } else {
        int dd = r - (NN + TIDC);
        float acc = 0.f;
        for (int i = 0; i < 10; ++i) acc = fmaf(DiW[dd * 10 + i], W_g1[(10 + i) * 64 + h], acc);
        D1[dd * 64 + h] = acc;
    }
}

// ---------------- K3: fused H_st + H + gate + X_spa -> X_T bf16 [b][j=l*32+d][n] ----------------
// block = 8 consecutive n at fixed (b,l); threads = 8 sites x 32 d
__global__ __launch_bounds__(256) void k_xspa(const float* __restrict__ hist,
                                              const float* __restrict__ hs,
                                              const float* __restrict__ W_emb,
                                              const float* __restrict__ b_emb,
                                              const float* __restrict__ W_st,
                                              const float* __restrict__ b_st,
                                              const float* __restrict__ U1,
                                              const float* __restrict__ T1,
                                              const float* __restrict__ D1,
                                              const float* __restrict__ W_g2,
                                              const float* __restrict__ b_g2,
                                              ushort* __restrict__ XT) {
    __shared__ float Wst_sm[96 * 32];
    __shared__ float hs_sm[8][96];
    __shared__ __align__(16) ushort Xs[32][8];
    int t = threadIdx.x;
    for (int i = t; i < 96 * 32; i += 256) Wst_sm[i] = W_st[i];
    int idx = blockIdx.x * 8;                  // site order (b,l,n)
    int b = idx / (LLEN * NN);
    int l = (idx / NN) % LLEN;
    int n0 = idx % NN;
    for (int i = t; i < 8 * 96; i += 256) {
        int s = i / 96, k = i % 96;
        hs_sm[s][k] = hs[(((size_t)b * NN + n0 + s) * LLEN + l) * 96 + k];
    }
    __syncthreads();
    int ls = t >> 5, d = t & 31;
    int n = n0 + ls;
    float acc = b_st[d];
#pragma unroll 8
    for (int k = 0; k < 96; ++k) acc = fmaf(hs_sm[ls][k], Wst_sm[k * 32 + d], acc);
    size_t hidx = (((size_t)b * LLEN + l) * NN + n) * 3;
    float x0 = hist[hidx + 0];
    float x1 = hist[hidx + 1];
    float x2 = hist[hidx + 2] * (1.0f / 7.0f);
    int ti = (int)(x1 * 288.0f); ti = ti < 0 ? 0 : (ti > 287 ? 287 : ti);
    int di = (int)(x2 * 7.0f);   di = di < 0 ? 0 : (di > 6 ? 6 : di);
    float H = fmaxf(fmaf(x0, W_emb[d], b_emb[d]) + acc, 0.f);
    float g0 = U1[n * 64 + d] + T1[ti * 64 + d] + D1[di * 64 + d];
    float g1 = U1[n * 64 + 32 + d] + T1[ti * 64 + 32 + d] + D1[di * 64 + 32 + d];
    float gs = fmaxf(g0, 0.f) * W_g2[d] + fmaxf(g1, 0.f) * W_g2[32 + d];
#pragma unroll
    for (int m = 16; m >= 1; m >>= 1) gs += __shfl_xor(gs, m, 64);
    float gate = 1.f / (1.f + __expf(-(gs + b_g2[0])));
    Xs[d][ls] = f2bf(H * gate);
    __syncthreads();
    if (t < 32) {
        short8 v = *(const short8*)&Xs[t][0];
        *(short8*)&XT[((size_t)b * NJ + l * 32 + t) * NN + n0] = v;
    }
}

// ---------------- K4: MFMA diffusion step, D[j,n] = sum_k InT[j,k]*W[k,n], W[k,n]=support[n,k] ----------------
// tile 64j x 64n, BK=32; 4 waves each 32x32 (2x2 frags of 16x16x32)
__global__ __launch_bounds__(256) void k_diff_mfma(const ushort* __restrict__ W,   // bf16 rows [n][k]
                                                   int w_batched,
                                                   const float* __restrict__ deg,  // null => no residual
                                                   const ushort* __restrict__ In,  // bf16 [b][384][1024]
                                                   ushort* __restrict__ Out) {
    __shared__ __align__(16) ushort As[64 * 40];
    __shared__ __align__(16) ushort Ws[64 * 40];
    int b = blockIdx.z;
    int j0 = blockIdx.x * 64;
    int n0 = blockIdx.y * 64;
    const ushort* Inb = In + (size_t)b * NJ * NN;
    const ushort* Wb = W + (w_batched ? (size_t)b * NN * NN : 0);
    int t = threadIdx.x;
    int srow = t >> 2, schunk = t & 3;
    int w = t >> 6;
    int wj = (w >> 1) * 32, wn = (w & 1) * 32;
    int l = t & 63;
    int lr = l & 15, lg = l >> 4;
    f32x4 acc[2][2];
#pragma unroll
    for (int i = 0; i < 2; ++i)
#pragma unroll
        for (int j = 0; j < 2; ++j) acc[i][j] = (f32x4){0.f, 0.f, 0.f, 0.f};

    for (int k0 = 0; k0 < NN; k0 += 32) {
        __syncthreads();
        *(short8*)&As[srow * 40 + schunk * 8] =
            *(const short8*)&Inb[(size_t)(j0 + srow) * NN + k0 + schunk * 8];
        *(short8*)&Ws[srow * 40 + schunk * 8] =
            *(const short8*)&Wb[(size_t)(n0 + srow) * NN + k0 + schunk * 8];
        __syncthreads();
        short8 a0 = *(const short8*)&As[(wj + lr) * 40 + lg * 8];
        short8 a1 = *(const short8*)&As[(wj + 16 + lr) * 40 + lg * 8];
        short8 b0 = *(const short8*)&Ws[(wn + lr) * 40 + lg * 8];
        short8 b1 = *(const short8*)&Ws[(wn + 16 + lr) * 40 + lg * 8];
        acc[0][0] = __builtin_amdgcn_mfma_f32_16x16x32_bf16(a0, b0, acc[0][0], 0, 0, 0);
        acc[0][1] = __builtin_amdgcn_mfma_f32_16x16x32_bf16(a0, b1, acc[0][1], 0, 0, 0);
        acc[1][0] = __builtin_amdgcn_mfma_f32_16x16x32_bf16(a1, b0, acc[1][0], 0, 0, 0);
        acc[1][1] = __builtin_amdgcn_mfma_f32_16x16x32_bf16(a1, b1, acc[1][1], 0, 0, 0);
    }
    ushort* Outb = Out + (size_t)b * NJ * NN;
    bool resid = (deg != nullptr);
#pragma unroll
    for (int nf = 0; nf < 2; ++nf) {
        int n_g = n0 + wn + nf * 16 + lr;
        float scale = 1.f;
        if (resid) scale = 1.f / (deg[b * NN + n_g] + 1.f);
#pragma unroll
        for (int jf = 0; jf < 2; ++jf) {
#pragma unroll
            for (int r = 0; r < 4; ++r) {
                int j_g = j0 + wj + jf * 16 + lg * 4 + r;
                float v = acc[jf][nf][r];
                if (resid) v += bf2f(Inb[(size_t)j_g * NN + n_g]);
                v *= scale;
                Outb[(size_t)j_g * NN + n_g] = f2bf(v);
            }
        }
    }
}

// ---------------- K5a: out = b_dif + X @ W_dif[0:32]  (reads X_T bf16) ----------------
__global__ __launch_bounds__(256) void k_out0(const ushort* __restrict__ XT,
                                              const float* __restrict__ W_dif,
                                              const float* __restrict__ b_dif,
                                              float* __restrict__ out) {
    __shared__ float xs[32][64];
    __shared__ float w0[32 * 32];
    int t = threadIdx.x;
    int n0 = blockIdx.x * 64;
    int l = blockIdx.y;
    int b = blockIdx.z;
    for (int i = t; i < 1024; i += 256) w0[i] = W_dif[i];
    {
        int jr = t >> 3, ch = t & 7;
        short8 v = *(const short8*)&XT[((size_t)b * NJ + l * 32 + jr) * NN + n0 + ch * 8];
#pragma unroll
        for (int q = 0; q < 8; ++q) xs[jr][ch * 8 + q] = bf2f((ushort)v[q]);
    }
    __syncthreads();
    int d = t & 31, nl = t >> 5;
    float acc[8];
#pragma unroll
    for (int i = 0; i < 8; ++i) acc[i] = b_dif[d];
    for (int j = 0; j < 32; ++j) {
        float wv = w0[j * 32 + d];
#pragma unroll
        for (int i = 0; i < 8; ++i) acc[i] = fmaf(xs[j][nl + 8 * i], wv, acc[i]);
    }
#pragma unroll
    for (int i = 0; i < 8; ++i)
        out[(((size_t)b * LLEN + l) * NN + n0 + nl + 8 * i) * 32 + d] = acc[i];
}

// ---------------- K5b: out += Z1 @ W_dif[row0:+32] + Z2 @ W_dif[row0+32:+32] (Z in T-layout bf16) ----------------
__global__ __launch_bounds__(256) void k_zout(const ushort* __restrict__ Z1,
                                              const ushort* __restrict__ Z2,
                                              const float* __restrict__ W_dif,
                                              int row0,
                                              float* __restrict__ out) {
    __shared__ float z1s[32][64];
    __shared__ float z2s[32][64];
    __shared__ float w1s[32 * 32];
    __shared__ float w2s[32 * 32];
    int t = threadIdx.x;
    int n0 = blockIdx.x * 64;
    int l = blockIdx.y;
    int b = blockIdx.z;
    for (int i = t; i < 1024; i += 256) {
        w1s[i] = W_dif[(size_t)row0 * 32 + i];
        w2s[i] = W_dif[(size_t)(row0 + 32) * 32 + i];
    }
    {
        int jr = t >> 3, ch = t & 7;
        size_t base = ((size_t)b * NJ + l * 32 + jr) * NN + n0 + ch * 8;
        short8 v1 = *(const short8*)&Z1[base];
        short8 v2 = *(const short8*)&Z2[base];
#pragma unroll
        for (int q = 0; q < 8; ++q) {
            z1s[jr][ch * 8 + q] = bf2f((ushort)v1[q]);
            z2s[jr][ch * 8 + q] = bf2f((ushort)v2[q]);
        }
    }
    __syncthreads();
    int d = t & 31, nl = t >> 5;
    float acc[8] = {0.f, 0.f, 0.f, 0.f, 0.f, 0.f, 0.f, 0.f};
    for (int j = 0; j < 32; ++j) {
        float wa = w1s[j * 32 + d];
        float wb = w2s[j * 32 + d];
#pragma unroll
        for (int i = 0; i < 8; ++i) {
            acc[i] = fmaf(z1s[j][nl + 8 * i], wa, acc[i]);
            acc[i] = fmaf(z2s[j][nl + 8 * i], wb, acc[i]);
        }
    }
#pragma unroll
    for (int i = 0; i < 8; ++i) {
        size_t oi = (((size_t)b * LLEN + l) * NN + n0 + nl + 8 * i) * 32 + d;
        out[oi] += acc[i];
    }
}

// ---------------- K6a: adj f32 -> bf16 (row order) ----------------
__global__ __launch_bounds__(256) void k_cvt_bf(const float* __restrict__ a, ushort* __restrict__ o) {
    const int total4 = (BBATCH * NN * NN) / 4;
    for (int i = blockIdx.x * 256 + threadIdx.x; i < total4; i += gridDim.x * 256) {
        float4 v = reinterpret_cast<const float4*>(a)[i];
        unsigned lo = (unsigned)f2bf(v.x) | ((unsigned)f2bf(v.y) << 16);
        unsigned hi = (unsigned)f2bf(v.z) | ((unsigned)f2bf(v.w) << 16);
        reinterpret_cast<uint2*>(o)[i] = make_uint2(lo, hi);
    }
}

// ---------------- K6b: adjT_bf16[b][n][k] = bf16(adj[b][k][n]) ----------------
__global__ __launch_bounds__(256) void k_transpose_bf(const float* __restrict__ adj,
                                                      ushort* __restrict__ adjT) {
    __shared__ float tile[64][65];
    int b = blockIdx.z;
    int r0 = blockIdx.y * 64, c0 = blockIdx.x * 64;
    int t = threadIdx.x;
    int c = t & 63, rbase = t >> 6;
#pragma unroll
    for (int i = 0; i < 16; ++i) {
        int r = rbase + i * 4;
        tile[r][c] = adj[((size_t)b * NN + r0 + r) * NN + c0 + c];
    }
    __syncthreads();
    int j = t >> 2, ch = t & 3;
    short8 o0, o1;
#pragma unroll
    for (int q = 0; q < 8; ++q) o0[q] = (short)f2bf(tile[ch * 16 + q][j]);
#pragma unroll
    for (int q = 0; q < 8; ++q) o1[q] = (short)f2bf(tile[ch * 16 + 8 + q][j]);
    size_t orow = ((size_t)b * NN + c0 + j) * NN + r0 + ch * 16;
    *(short8*)&adjT[orow] = o0;
    *(short8*)&adjT[orow + 8] = o1;
}

extern "C" void kernel_launch(void* const* d_in, const int* in_sizes, int n_in,
                              void* d_out, int out_size, void* d_ws, size_t ws_size,
                              hipStream_t stream) {
    (void)in_sizes; (void)n_in; (void)out_size; (void)ws_size;
    const float* hist  = (const float*)d_in[0];
    const float* hs    = (const float*)d_in[1];
    const float* adj   = (const float*)d_in[2];
    const float* W_emb = (const float*)d_in[3];
    const float* b_emb = (const float*)d_in[4];
    const float* W_st  = (const float*)d_in[5];
    const float* b_st  = (const float*)d_in[6];
    const float* TiD   = (const float*)d_in[7];
    const float* DiW   = (const float*)d_in[8];
    const float* emb_u = (const float*)d_in[9];
    const float* emb_d = (const float*)d_in[10];
    const float* W_g1  = (const float*)d_in[11];
    const float* b_g1  = (const float*)d_in[12];
    const float* W_g2  = (const float*)d_in[13];
    const float* b_g2  = (const float*)d_in[14];
    const float* W_dif = (const float*)d_in[15];
    const float* b_dif = (const float*)d_in[16];
    float* out = (float*)d_out;

    // ws layout (bytes), total 20,293,376 B (~19.4 MB)
    uint8_t* w8 = (uint8_t*)d_ws;
    ushort* adjbuf = (ushort*)w8;                   // 8 MB: adj_bf16, later overwritten by adjT_bf16
    ushort* S_bf   = (ushort*)(w8 + 8388608);       // 2 MB
    ushort* XT     = (ushort*)(w8 + 10485760);      // 3 MB
    ushort* Z1     = (ushort*)(w8 + 13631488);      // 3 MB
    ushort* Z2     = (ushort*)(w8 + 16777216);      // 3 MB
    float*  rs     = (float*)(w8 + 19922944);
    float*  cs     = (float*)(w8 + 19939328);
    float*  U1     = (float*)(w8 + 19955712);
    float*  T1     = (float*)(w8 + 20217856);
    float*  D1     = (float*)(w8 + 20291584);

    hipMemsetAsync(cs, 0, BBATCH * NN * sizeof(float), stream);
    k_rowsum<<<BBATCH * NN, 256, 0, stream>>>(adj, rs);
    k_colsum<<<dim3(4, 16, 4), 256, 0, stream>>>(adj, cs);
    k_gate_pre<<<NN + TIDC + DIWC, 64, 0, stream>>>(emb_u, emb_d, W_g1, b_g1, TiD, DiW, U1, T1, D1);
    k_static<<<NN, 256, 0, stream>>>(emb_u, emb_d, S_bf);
    k_xspa<<<6144, 256, 0, stream>>>(hist, hs, W_emb, b_emb, W_st, b_st, U1, T1, D1, W_g2, b_g2, XT);
    k_out0<<<dim3(16, 12, 4), 256, 0, stream>>>(XT, W_dif, b_dif, out);

    dim3 dgrid(6, 16, 4);
    // fwd chain (uses adj_bf16 rows, deg=rs)
    k_cvt_bf<<<2048, 256, 0, stream>>>(adj, adjbuf);
    k_diff_mfma<<<dgrid, 256, 0, stream>>>(adjbuf, 1, rs, XT, Z1);
    k_diff_mfma<<<dgrid, 256, 0, stream>>>(adjbuf, 1, rs, Z1, Z2);
    k_zout<<<dim3(16, 12, 4), 256, 0, stream>>>(Z1, Z2, W_dif, 96, out);
    // bwd chain (uses adjT_bf16 rows, deg=cs) -- adjbuf overwritten after fwd chain done
    k_transpose_bf<<<dim3(16, 16, 4), 256, 0, stream>>>(adj, adjbuf);
    k_diff_mfma<<<dgrid, 256, 0, stream>>>(adjbuf, 1, cs, XT, Z1);
    k_diff_mfma<<<dgrid, 256, 0, stream>>>(adjbuf, 1, cs, Z1, Z2);
    k_zout<<<dim3(16, 12, 4), 256, 0, stream>>>(Z1, Z2, W_dif, 160, out);
    // static chain (uses S_bf rows, no residual)
    k_diff_mfma<<<dgrid, 256, 0, stream>>>(S_bf, 0, nullptr, XT, Z1);
    k_diff_mfma<<<dgrid, 256, 0, stream>>>(S_bf, 0, nullptr, Z1, Z2);
    k_zout<<<dim3(16, 12, 4), 256, 0, stream>>>(Z1, Z2, W_dif, 32, out);
}

// Round 4
// 274.592 us; speedup vs baseline: 2.3371x; 1.1897x over previous
//
#include <hip/hip_runtime.h>
#include <hip/hip_bf16.h>
#include <cstdint>

#define NN 1024
#define BBATCH 4
#define LLEN 12
#define NJ 384   // LLEN*32
#define TIDC 288
#define DIWC 7

typedef __attribute__((ext_vector_type(8))) short short8;
typedef __attribute__((ext_vector_type(4))) float f32x4;

__device__ inline ushort f2bf(float f) {
    unsigned u = __float_as_uint(f);
    u += 0x7FFFu + ((u >> 16) & 1u);
    return (ushort)(u >> 16);
}
__device__ inline float bf2f(ushort u) { return __uint_as_float(((unsigned)u) << 16); }

// ---------------- K1: static support S = softmax(relu(emb_d @ emb_u^T), axis=1), bf16 out ----------------
__global__ __launch_bounds__(256) void k_static(const float* __restrict__ emb_u,
                                                const float* __restrict__ emb_d,
                                                ushort* __restrict__ S_bf) {
    int i = blockIdx.x;
    int t = threadIdx.x;
    __shared__ float drow[32];
    __shared__ float red[256];
    if (t < 32) drow[t] = emb_d[i * 32 + t];
    __syncthreads();
    float v[4];
    float lsum = 0.f;
    for (int jj = 0; jj < 4; ++jj) {
        int j = jj * 256 + t;
        const float4* u4 = reinterpret_cast<const float4*>(emb_u + (size_t)j * 32);
        float acc = 0.f;
#pragma unroll
        for (int k4 = 0; k4 < 8; ++k4) {
            float4 u = u4[k4];
            acc += drow[k4 * 4 + 0] * u.x + drow[k4 * 4 + 1] * u.y +
                   drow[k4 * 4 + 2] * u.z + drow[k4 * 4 + 3] * u.w;
        }
        acc = fmaxf(acc, 0.f);
        v[jj] = __expf(acc);
        lsum += v[jj];
    }
    red[t] = lsum;
    __syncthreads();
    for (int s = 128; s > 0; s >>= 1) {
        if (t < s) red[t] += red[t + s];
        __syncthreads();
    }
    float inv = 1.f / red[0];
    for (int jj = 0; jj < 4; ++jj) S_bf[(size_t)i * NN + jj * 256 + t] = f2bf(v[jj] * inv);
}

// ---------------- K2a: raw row sums of adj ----------------
__global__ __launch_bounds__(256) void k_rowsum(const float* __restrict__ adj, float* __restrict__ rs) {
    int row = blockIdx.x;    // B*N
    const float* p = adj + (size_t)row * NN;
    int t = threadIdx.x;
    float s = p[t] + p[t + 256] + p[t + 512] + p[t + 768];
    __shared__ float red[256];
    red[t] = s;
    __syncthreads();
    for (int k = 128; k > 0; k >>= 1) {
        if (t < k) red[t] += red[t + k];
        __syncthreads();
    }
    if (t == 0) rs[row] = red[0];
}

// ---------------- K2b: raw col sums of adj (atomic partials; cs pre-zeroed) ----------------
__global__ __launch_bounds__(256) void k_colsum(const float* __restrict__ adj, float* __restrict__ cs) {
    int b = blockIdx.z;
    int j = blockIdx.x * 256 + threadIdx.x;
    int i0 = blockIdx.y * 64;
    const float* p = adj + ((size_t)b * NN + i0) * NN + j;
    float s = 0.f;
    for (int i = 0; i < 64; ++i) s += p[(size_t)i * NN];
    atomicAdd(&cs[b * NN + j], s);
}

// ---------------- K0: gate-MLP layer-1 tables ----------------
__global__ __launch_bounds__(64) void k_gate_pre(const float* __restrict__ emb_u,
                                                 const float* __restrict__ emb_d,
                                                 const float* __restrict__ W_g1,
                                                 const float* __restrict__ b_g1,
                                                 const float* __restrict__ TiD,
                                                 const float* __restrict__ DiW,
                                                 float* __restrict__ U1, float* __restrict__ T1,
                                                 float* __restrict__ D1) {
    int r = blockIdx.x;
    int h = threadIdx.x;   // 64
    if (r < NN) {
        float acc = b_g1[h];
        for (int i = 0; i < 32; ++i) acc = fmaf(emb_u[r * 32 + i], W_g1[(20 + i) * 64 + h], acc);
        for (int i = 0; i < 32; ++i) acc = fmaf(emb_d[r * 32 + i], W_g1[(52 + i) * 64 + h], acc);
        U1[r * 64 + h] = acc;
    } else if (r < NN + TIDC) {
        int tt = r - NN;
        float acc = 0.f;
        for (int i = 0; i < 10; ++i) acc = fmaf(TiD[tt * 10 + i], W_g1[i * 64 + h], acc);
        T1[tt * 64 + h] = acc;
    } else {
        int dd = r - (NN + TIDC);
        float acc = 0.f;
        for (int i = 0; i < 10; ++i) acc = fmaf(DiW[dd * 10 + i], W_g1[(10 + i) * 64 + h], acc);
        D1[dd * 64 + h] = acc;
    }
}

// ---------------- K3: fused H_st + H + gate + X_spa -> X_T bf16 [b][j=l*32+d][n] ----------------
__global__ __launch_bounds__(256) void k_xspa(const float* __restrict__ hist,
                                              const float* __restrict__ hs,
                                              const float* __restrict__ W_emb,
                                              const float* __restrict__ b_emb,
                                              const float* __restrict__ W_st,
                                              const float* __restrict__ b_st,
                                              const float* __restrict__ U1,
                                              const float* __restrict__ T1,
                                              const float* __restrict__ D1,
                                              const float* __restrict__ W_g2,
                                              const float* __restrict__ b_g2,
                                              ushort* __restrict__ XT) {
    __shared__ float Wst_sm[96 * 32];
    __shared__ float hs_sm[8][96];
    __shared__ __align__(16) ushort Xs[32][8];
    int t = threadIdx.x;
    for (int i = t; i < 96 * 32; i += 256) Wst_sm[i] = W_st[i];
    int idx = blockIdx.x * 8;                  // site order (b,l,n)
    int b = idx / (LLEN * NN);
    int l = (idx / NN) % LLEN;
    int n0 = idx % NN;
    for (int i = t; i < 8 * 96; i += 256) {
        int s = i / 96, k = i % 96;
        hs_sm[s][k] = hs[(((size_t)b * NN + n0 + s) * LLEN + l) * 96 + k];
    }
    __syncthreads();
    int ls = t >> 5, d = t & 31;
    int n = n0 + ls;
    float acc = b_st[d];
#pragma unroll 8
    for (int k = 0; k < 96; ++k) acc = fmaf(hs_sm[ls][k], Wst_sm[k * 32 + d], acc);
    size_t hidx = (((size_t)b * LLEN + l) * NN + n) * 3;
    float x0 = hist[hidx + 0];
    float x1 = hist[hidx + 1];
    float x2 = hist[hidx + 2] * (1.0f / 7.0f);
    int ti = (int)(x1 * 288.0f); ti = ti < 0 ? 0 : (ti > 287 ? 287 : ti);
    int di = (int)(x2 * 7.0f);   di = di < 0 ? 0 : (di > 6 ? 6 : di);
    float H = fmaxf(fmaf(x0, W_emb[d], b_emb[d]) + acc, 0.f);
    float g0 = U1[n * 64 + d] + T1[ti * 64 + d] + D1[di * 64 + d];
    float g1 = U1[n * 64 + 32 + d] + T1[ti * 64 + 32 + d] + D1[di * 64 + 32 + d];
    float gs = fmaxf(g0, 0.f) * W_g2[d] + fmaxf(g1, 0.f) * W_g2[32 + d];
#pragma unroll
    for (int m = 16; m >= 1; m >>= 1) gs += __shfl_xor(gs, m, 64);
    float gate = 1.f / (1.f + __expf(-(gs + b_g2[0])));
    Xs[d][ls] = f2bf(H * gate);
    __syncthreads();
    if (t < 32) {
        short8 v = *(const short8*)&Xs[t][0];
        *(short8*)&XT[((size_t)b * NJ + l * 32 + t) * NN + n0] = v;
    }
}

// ---------------- K4: MFMA diffusion step, ALL supports in one launch, 2-phase pipelined ----------------
// z = s*4 + b; s=0 static (S_bf, no resid), s=1 fwd (adjF, rs), s=2 bwd (adjT, cs)
// D[j,n] = sum_k InT[j,k]*W[k,n] with W[k,n] = support[n,k] (rows staged from [n][k] bf16 matrices)
__global__ __launch_bounds__(256) void k_diff2(const ushort* __restrict__ S_bf,
                                               const ushort* __restrict__ adjF,
                                               const ushort* __restrict__ adjT,
                                               const float* __restrict__ rs,
                                               const float* __restrict__ cs,
                                               const ushort* __restrict__ In0,
                                               int in_per_chain,
                                               ushort* __restrict__ Out0) {
    __shared__ __align__(16) ushort As[2][64 * 40];
    __shared__ __align__(16) ushort Ws[2][64 * 40];
    int z = blockIdx.z;
    int s = z >> 2, b = z & 3;
    int j0 = blockIdx.x * 64;
    int n0 = blockIdx.y * 64;
    const size_t ZT = (size_t)BBATCH * NJ * NN;
    const ushort* Wb = (s == 0) ? S_bf
                     : (s == 1) ? adjF + (size_t)b * NN * NN
                                : adjT + (size_t)b * NN * NN;
    const float* deg = (s == 0) ? nullptr : (s == 1 ? rs : cs);
    const ushort* Inb = In0 + (in_per_chain ? (size_t)s * ZT : 0) + (size_t)b * NJ * NN;
    ushort* Outb = Out0 + (size_t)s * ZT + (size_t)b * NJ * NN;

    int t = threadIdx.x;
    int row = t >> 2, ch = (t & 3) * 8;
    const ushort* pA = Inb + (size_t)(j0 + row) * NN + ch;
    const ushort* pW = Wb + (size_t)(n0 + row) * NN + ch;
    int w = t >> 6;
    int wjj = (w >> 1) * 32, wnn = (w & 1) * 32;
    int l = t & 63, lr = l & 15, lg = l >> 4;
    f32x4 acc[2][2];
#pragma unroll
    for (int i = 0; i < 2; ++i)
#pragma unroll
        for (int j = 0; j < 2; ++j) acc[i][j] = (f32x4){0.f, 0.f, 0.f, 0.f};

    // prologue: stage tile 0
    {
        short8 ar = *(const short8*)pA;
        short8 wr = *(const short8*)pW;
        *(short8*)&As[0][row * 40 + ch] = ar;
        *(short8*)&Ws[0][row * 40 + ch] = wr;
    }
    __syncthreads();
    int cur = 0;
    for (int kt = 0; kt < 32; ++kt) {
        short8 an, wn2;
        if (kt < 31) {                       // issue next tile's loads early
            an = *(const short8*)(pA + (size_t)(kt + 1) * 32);
            wn2 = *(const short8*)(pW + (size_t)(kt + 1) * 32);
        }
        short8 a0 = *(const short8*)&As[cur][(wjj + lr) * 40 + lg * 8];
        short8 a1 = *(const short8*)&As[cur][(wjj + 16 + lr) * 40 + lg * 8];
        short8 b0 = *(const short8*)&Ws[cur][(wnn + lr) * 40 + lg * 8];
        short8 b1 = *(const short8*)&Ws[cur][(wnn + 16 + lr) * 40 + lg * 8];
        acc[0][0] = __builtin_amdgcn_mfma_f32_16x16x32_bf16(a0, b0, acc[0][0], 0, 0, 0);
        acc[0][1] = __builtin_amdgcn_mfma_f32_16x16x32_bf16(a0, b1, acc[0][1], 0, 0, 0);
        acc[1][0] = __builtin_amdgcn_mfma_f32_16x16x32_bf16(a1, b0, acc[1][0], 0, 0, 0);
        acc[1][1] = __builtin_amdgcn_mfma_f32_16x16x32_bf16(a1, b1, acc[1][1], 0, 0, 0);
        if (kt < 31) {                       // write next tile into alternate buffer
            *(short8*)&As[cur ^ 1][row * 40 + ch] = an;
            *(short8*)&Ws[cur ^ 1][row * 40 + ch] = wn2;
        }
        __syncthreads();
        cur ^= 1;
    }
    bool resid = (deg != nullptr);
#pragma unroll
    for (int nf = 0; nf < 2; ++nf) {
        int n_g = n0 + wnn + nf * 16 + lr;
        float scale = 1.f;
        if (resid) scale = 1.f / (deg[b * NN + n_g] + 1.f);
#pragma unroll
        for (int jf = 0; jf < 2; ++jf) {
#pragma unroll
            for (int r = 0; r < 4; ++r) {
                int j_g = j0 + wjj + jf * 16 + lg * 4 + r;
                float v = acc[jf][nf][r];
                if (resid) v += bf2f(Inb[(size_t)j_g * NN + n_g]);
                v *= scale;
                Outb[(size_t)j_g * NN + n_g] = f2bf(v);
            }
        }
    }
}

// ---------------- K5a: out = b_dif + X @ W_dif[0:32]  (reads X_T bf16) ----------------
__global__ __launch_bounds__(256) void k_out0(const ushort* __restrict__ XT,
                                              const float* __restrict__ W_dif,
                                              const float* __restrict__ b_dif,
                                              float* __restrict__ out) {
    __shared__ float xs[32][64];
    __shared__ float w0[32 * 32];
    int t = threadIdx.x;
    int n0 = blockIdx.x * 64;
    int l = blockIdx.y;
    int b = blockIdx.z;
    for (int i = t; i < 1024; i += 256) w0[i] = W_dif[i];
    {
        int jr = t >> 3, ch = t & 7;
        short8 v = *(const short8*)&XT[((size_t)b * NJ + l * 32 + jr) * NN + n0 + ch * 8];
#pragma unroll
        for (int q = 0; q < 8; ++q) xs[jr][ch * 8 + q] = bf2f((ushort)v[q]);
    }
    __syncthreads();
    int d = t & 31, nl = t >> 5;
    float acc[8];
#pragma unroll
    for (int i = 0; i < 8; ++i) acc[i] = b_dif[d];
    for (int j = 0; j < 32; ++j) {
        float wv = w0[j * 32 + d];
#pragma unroll
        for (int i = 0; i < 8; ++i) acc[i] = fmaf(xs[j][nl + 8 * i], wv, acc[i]);
    }
#pragma unroll
    for (int i = 0; i < 8; ++i)
        out[(((size_t)b * LLEN + l) * NN + n0 + nl + 8 * i) * 32 + d] = acc[i];
}

// ---------------- K5b: out += Z1 @ W_dif[row0:+32] + Z2 @ W_dif[row0+32:+32] (Z in T-layout bf16) ----------------
__global__ __launch_bounds__(256) void k_zout(const ushort* __restrict__ Z1,
                                              const ushort* __restrict__ Z2,
                                              const float* __restrict__ W_dif,
                                              int row0,
                                              float* __restrict__ out) {
    __shared__ float z1s[32][64];
    __shared__ float z2s[32][64];
    __shared__ float w1s[32 * 32];
    __shared__ float w2s[32 * 32];
    int t = threadIdx.x;
    int n0 = blockIdx.x * 64;
    int l = blockIdx.y;
    int b = blockIdx.z;
    for (int i = t; i < 1024; i += 256) {
        w1s[i] = W_dif[(size_t)row0 * 32 + i];
        w2s[i] = W_dif[(size_t)(row0 + 32) * 32 + i];
    }
    {
        int jr = t >> 3, ch = t & 7;
        size_t base = ((size_t)b * NJ + l * 32 + jr) * NN + n0 + ch * 8;
        short8 v1 = *(const short8*)&Z1[base];
        short8 v2 = *(const short8*)&Z2[base];
#pragma unroll
        for (int q = 0; q < 8; ++q) {
            z1s[jr][ch * 8 + q] = bf2f((ushort)v1[q]);
            z2s[jr][ch * 8 + q] = bf2f((ushort)v2[q]);
        }
    }
    __syncthreads();
    int d = t & 31, nl = t >> 5;
    float acc[8] = {0.f, 0.f, 0.f, 0.f, 0.f, 0.f, 0.f, 0.f};
    for (int j = 0; j < 32; ++j) {
        float wa = w1s[j * 32 + d];
        float wb = w2s[j * 32 + d];
#pragma unroll
        for (int i = 0; i < 8; ++i) {
            acc[i] = fmaf(z1s[j][nl + 8 * i], wa, acc[i]);
            acc[i] = fmaf(z2s[j][nl + 8 * i], wb, acc[i]);
        }
    }
#pragma unroll
    for (int i = 0; i < 8; ++i) {
        size_t oi = (((size_t)b * LLEN + l) * NN + n0 + nl + 8 * i) * 32 + d;
        out[oi] += acc[i];
    }
}

// ---------------- K6a: adj f32 -> bf16 (row order) ----------------
__global__ __launch_bounds__(256) void k_cvt_bf(const float* __restrict__ a, ushort* __restrict__ o) {
    const int total4 = (BBATCH * NN * NN) / 4;
    for (int i = blockIdx.x * 256 + threadIdx.x; i < total4; i += gridDim.x * 256) {
        float4 v = reinterpret_cast<const float4*>(a)[i];
        unsigned lo = (unsigned)f2bf(v.x) | ((unsigned)f2bf(v.y) << 16);
        unsigned hi = (unsigned)f2bf(v.z) | ((unsigned)f2bf(v.w) << 16);
        reinterpret_cast<uint2*>(o)[i] = make_uint2(lo, hi);
    }
}

// ---------------- K6b: adjT_bf16[b][n][k] = bf16(adj[b][k][n]) ----------------
__global__ __launch_bounds__(256) void k_transpose_bf(const float* __restrict__ adj,
                                                      ushort* __restrict__ adjT) {
    __shared__ float tile[64][65];
    int b = blockIdx.z;
    int r0 = blockIdx.y * 64, c0 = blockIdx.x * 64;
    int t = threadIdx.x;
    int c = t & 63, rbase = t >> 6;
#pragma unroll
    for (int i = 0; i < 16; ++i) {
        int r = rbase + i * 4;
        tile[r][c] = adj[((size_t)b * NN + r0 + r) * NN + c0 + c];
    }
    __syncthreads();
    int j = t >> 2, ch = t & 3;
    short8 o0, o1;
#pragma unroll
    for (int q = 0; q < 8; ++q) o0[q] = (short)f2bf(tile[ch * 16 + q][j]);
#pragma unroll
    for (int q = 0; q < 8; ++q) o1[q] = (short)f2bf(tile[ch * 16 + 8 + q][j]);
    size_t orow = ((size_t)b * NN + c0 + j) * NN + r0 + ch * 16;
    *(short8*)&adjT[orow] = o0;
    *(short8*)&adjT[orow + 8] = o1;
}

extern "C" void kernel_launch(void* const* d_in, const int* in_sizes, int n_in,
                              void* d_out, int out_size, void* d_ws, size_t ws_size,
                              hipStream_t stream) {
    (void)in_sizes; (void)n_in; (void)out_size; (void)ws_size;
    const float* hist  = (const float*)d_in[0];
    const float* hs    = (const float*)d_in[1];
    const float* adj   = (const float*)d_in[2];
    const float* W_emb = (const float*)d_in[3];
    const float* b_emb = (const float*)d_in[4];
    const float* W_st  = (const float*)d_in[5];
    const float* b_st  = (const float*)d_in[6];
    const float* TiD   = (const float*)d_in[7];
    const float* DiW   = (const float*)d_in[8];
    const float* emb_u = (const float*)d_in[9];
    const float* emb_d = (const float*)d_in[10];
    const float* W_g1  = (const float*)d_in[11];
    const float* b_g1  = (const float*)d_in[12];
    const float* W_g2  = (const float*)d_in[13];
    const float* b_g2  = (const float*)d_in[14];
    const float* W_dif = (const float*)d_in[15];
    const float* b_dif = (const float*)d_in[16];
    float* out = (float*)d_out;

    // ws layout (bytes), total ~38.6 MB (ws_size ~268 MB per fill evidence)
    uint8_t* w8 = (uint8_t*)d_ws;
    ushort* adjF = (ushort*)w8;                      // 8 MB  adj bf16 [b][n][k]
    ushort* adjT = (ushort*)(w8 + 8388608);          // 8 MB  adj^T bf16 [b][n][k]
    ushort* S_bf = (ushort*)(w8 + 16777216);         // 2 MB
    ushort* XT   = (ushort*)(w8 + 18874368);         // 3 MB  [b][384][1024]
    ushort* Z1   = (ushort*)(w8 + 22020096);         // 9 MB  [s][b][384][1024]
    ushort* Z2   = (ushort*)(w8 + 31457280);         // 9 MB
    float*  rs   = (float*)(w8 + 40894464);          // 16 KB
    float*  cs   = (float*)(w8 + 40910848);          // 16 KB
    float*  U1   = (float*)(w8 + 40927232);          // 256 KB
    float*  T1   = (float*)(w8 + 41189376);          // 72 KB
    float*  D1   = (float*)(w8 + 41263104);          // 1.8 KB
    const size_t ZT = (size_t)BBATCH * NJ * NN;      // 1572864 elems per chain

    hipMemsetAsync(cs, 0, BBATCH * NN * sizeof(float), stream);
    k_rowsum<<<BBATCH * NN, 256, 0, stream>>>(adj, rs);
    k_colsum<<<dim3(4, 16, 4), 256, 0, stream>>>(adj, cs);
    k_gate_pre<<<NN + TIDC + DIWC, 64, 0, stream>>>(emb_u, emb_d, W_g1, b_g1, TiD, DiW, U1, T1, D1);
    k_static<<<NN, 256, 0, stream>>>(emb_u, emb_d, S_bf);
    k_cvt_bf<<<2048, 256, 0, stream>>>(adj, adjF);
    k_transpose_bf<<<dim3(16, 16, 4), 256, 0, stream>>>(adj, adjT);
    k_xspa<<<6144, 256, 0, stream>>>(hist, hs, W_emb, b_emb, W_st, b_st, U1, T1, D1, W_g2, b_g2, XT);
    k_out0<<<dim3(16, 12, 4), 256, 0, stream>>>(XT, W_dif, b_dif, out);

    // merged diffusion: step 1 (all supports read XT), step 2 (each reads own Z1)
    dim3 dgrid(6, 16, 12);
    k_diff2<<<dgrid, 256, 0, stream>>>(S_bf, adjF, adjT, rs, cs, XT, 0, Z1);
    k_diff2<<<dgrid, 256, 0, stream>>>(S_bf, adjF, adjT, rs, cs, Z1, 1, Z2);

    // epilogues (chain order in Z arrays: s=0 static, s=1 fwd, s=2 bwd)
    k_zout<<<dim3(16, 12, 4), 256, 0, stream>>>(Z1 + 0 * ZT, Z2 + 0 * ZT, W_dif, 32, out);
    k_zout<<<dim3(16, 12, 4), 256, 0, stream>>>(Z1 + 1 * ZT, Z2 + 1 * ZT, W_dif, 96, out);
    k_zout<<<dim3(16, 12, 4), 256, 0, stream>>>(Z1 + 2 * ZT, Z2 + 2 * ZT, W_dif, 160, out);
}

// Round 5
// 251.416 us; speedup vs baseline: 2.5525x; 1.0922x over previous
//
#include <hip/hip_runtime.h>
#include <hip/hip_bf16.h>
#include <cstdint>

#define NN 1024
#define BBATCH 4
#define LLEN 12
#define NJ 384   // LLEN*32
#define TIDC 288
#define DIWC 7

typedef __attribute__((ext_vector_type(8))) short short8;
typedef __attribute__((ext_vector_type(4))) float f32x4;

__device__ inline ushort f2bf(float f) {
    unsigned u = __float_as_uint(f);
    u += 0x7FFFu + ((u >> 16) & 1u);
    return (ushort)(u >> 16);
}
__device__ inline float bf2f(ushort u) { return __uint_as_float(((unsigned)u) << 16); }

// ---------------- K1: static support S = softmax(relu(emb_d @ emb_u^T), axis=1), bf16 out ----------------
__global__ __launch_bounds__(256) void k_static(const float* __restrict__ emb_u,
                                                const float* __restrict__ emb_d,
                                                ushort* __restrict__ S_bf) {
    int i = blockIdx.x;
    int t = threadIdx.x;
    __shared__ float drow[32];
    __shared__ float red[256];
    if (t < 32) drow[t] = emb_d[i * 32 + t];
    __syncthreads();
    float v[4];
    float lsum = 0.f;
    for (int jj = 0; jj < 4; ++jj) {
        int j = jj * 256 + t;
        const float4* u4 = reinterpret_cast<const float4*>(emb_u + (size_t)j * 32);
        float acc = 0.f;
#pragma unroll
        for (int k4 = 0; k4 < 8; ++k4) {
            float4 u = u4[k4];
            acc += drow[k4 * 4 + 0] * u.x + drow[k4 * 4 + 1] * u.y +
                   drow[k4 * 4 + 2] * u.z + drow[k4 * 4 + 3] * u.w;
        }
        acc = fmaxf(acc, 0.f);
        v[jj] = __expf(acc);
        lsum += v[jj];
    }
    red[t] = lsum;
    __syncthreads();
    for (int s = 128; s > 0; s >>= 1) {
        if (t < s) red[t] += red[t + s];
        __syncthreads();
    }
    float inv = 1.f / red[0];
    for (int jj = 0; jj < 4; ++jj) S_bf[(size_t)i * NN + jj * 256 + t] = f2bf(v[jj] * inv);
}

// ---------------- K2: fused adj preprocessing: adjF bf16, adjT bf16, row sums, col sums ----------------
// one read of fp32 adj per 64x64 tile; rs/cs must be pre-zeroed (atomic partials)
__global__ __launch_bounds__(256) void k_adj_pre(const float* __restrict__ adj,
                                                 ushort* __restrict__ adjF,
                                                 ushort* __restrict__ adjT,
                                                 float* __restrict__ rs,
                                                 float* __restrict__ cs) {
    __shared__ float tile[64][65];
    int b = blockIdx.z;
    int r0 = blockIdx.y * 64, c0 = blockIdx.x * 64;
    int t = threadIdx.x;
    int col = (t & 15) * 4, rb = t >> 4;
#pragma unroll
    for (int i = 0; i < 4; ++i) {
        int r = rb + i * 16;
        float4 v = *reinterpret_cast<const float4*>(&adj[((size_t)b * NN + r0 + r) * NN + c0 + col]);
        tile[r][col] = v.x; tile[r][col + 1] = v.y; tile[r][col + 2] = v.z; tile[r][col + 3] = v.w;
        unsigned lo = (unsigned)f2bf(v.x) | ((unsigned)f2bf(v.y) << 16);
        unsigned hi = (unsigned)f2bf(v.z) | ((unsigned)f2bf(v.w) << 16);
        *reinterpret_cast<uint2*>(&adjF[((size_t)b * NN + r0 + r) * NN + c0 + col]) = make_uint2(lo, hi);
    }
    __syncthreads();
    if (t < 64) {
        float s = 0.f;
        for (int c = 0; c < 64; ++c) s += tile[t][c];
        atomicAdd(&rs[b * NN + r0 + t], s);
    } else if (t < 128) {
        int c = t - 64;
        float s = 0.f;
        for (int r = 0; r < 64; ++r) s += tile[r][c];
        atomicAdd(&cs[b * NN + c0 + c], s);
    }
    int j = t >> 2, ch = t & 3;
    short8 o0, o1;
#pragma unroll
    for (int q = 0; q < 8; ++q) o0[q] = (short)f2bf(tile[ch * 16 + q][j]);
#pragma unroll
    for (int q = 0; q < 8; ++q) o1[q] = (short)f2bf(tile[ch * 16 + 8 + q][j]);
    size_t orow = ((size_t)b * NN + c0 + j) * NN + r0 + ch * 16;
    *(short8*)&adjT[orow] = o0;
    *(short8*)&adjT[orow + 8] = o1;
}

// ---------------- K0: gate-MLP layer-1 tables ----------------
__global__ __launch_bounds__(64) void k_gate_pre(const float* __restrict__ emb_u,
                                                 const float* __restrict__ emb_d,
                                                 const float* __restrict__ W_g1,
                                                 const float* __restrict__ b_g1,
                                                 const float* __restrict__ TiD,
                                                 const float* __restrict__ DiW,
                                                 float* __restrict__ U1, float* __restrict__ T1,
                                                 float* __restrict__ D1) {
    int r = blockIdx.x;
    int h = threadIdx.x;   // 64
    if (r < NN) {
        float acc = b_g1[h];
        for (int i = 0; i < 32; ++i) acc = fmaf(emb_u[r * 32 + i], W_g1[(20 + i) * 64 + h], acc);
        for (int i = 0; i < 32; ++i) acc = fmaf(emb_d[r * 32 + i], W_g1[(52 + i) * 64 + h], acc);
        U1[r * 64 + h] = acc;
    } else if (r < NN + TIDC) {
        int tt = r - NN;
        float acc = 0.f;
        for (int i = 0; i < 10; ++i) acc = fmaf(TiD[tt * 10 + i], W_g1[i * 64 + h], acc);
        T1[tt * 64 + h] = acc;
    } else {
        int dd = r - (NN + TIDC);
        float acc = 0.f;
        for (int i = 0; i < 10; ++i) acc = fmaf(DiW[dd * 10 + i], W_g1[(10 + i) * 64 + h], acc);
        D1[dd * 64 + h] = acc;
    }
}

// ---------------- K3: fused H_st + H + gate + X_spa -> XT bf16 [b][j][n]  AND  out[...,:] = b_dif + X@W_dif[0:32]
__global__ __launch_bounds__(256) void k_xspa(const float* __restrict__ hist,
                                              const float* __restrict__ hs,
                                              const float* __restrict__ W_emb,
                                              const float* __restrict__ b_emb,
                                              const float* __restrict__ W_st,
                                              const float* __restrict__ b_st,
                                              const float* __restrict__ U1,
                                              const float* __restrict__ T1,
                                              const float* __restrict__ D1,
                                              const float* __restrict__ W_g2,
                                              const float* __restrict__ b_g2,
                                              const float* __restrict__ W_dif,
                                              const float* __restrict__ b_dif,
                                              ushort* __restrict__ XT,
                                              float* __restrict__ out) {
    __shared__ float Wst_sm[96 * 32];
    __shared__ float W0s[32 * 32];
    __shared__ float hs_sm[8][96];
    __shared__ __align__(16) ushort Xs[32][8];
    int t = threadIdx.x;
    for (int i = t; i < 96 * 32; i += 256) Wst_sm[i] = W_st[i];
    for (int i = t; i < 1024; i += 256) W0s[i] = W_dif[i];
    int idx = blockIdx.x * 8;                  // site order (b,l,n)
    int b = idx / (LLEN * NN);
    int l = (idx / NN) % LLEN;
    int n0 = idx % NN;
    for (int i = t; i < 8 * 96; i += 256) {
        int s = i / 96, k = i % 96;
        hs_sm[s][k] = hs[(((size_t)b * NN + n0 + s) * LLEN + l) * 96 + k];
    }
    __syncthreads();
    int ls = t >> 5, d = t & 31;
    int n = n0 + ls;
    float acc = b_st[d];
#pragma unroll 8
    for (int k = 0; k < 96; ++k) acc = fmaf(hs_sm[ls][k], Wst_sm[k * 32 + d], acc);
    size_t hidx = (((size_t)b * LLEN + l) * NN + n) * 3;
    float x0 = hist[hidx + 0];
    float x1 = hist[hidx + 1];
    float x2 = hist[hidx + 2] * (1.0f / 7.0f);
    int ti = (int)(x1 * 288.0f); ti = ti < 0 ? 0 : (ti > 287 ? 287 : ti);
    int di = (int)(x2 * 7.0f);   di = di < 0 ? 0 : (di > 6 ? 6 : di);
    float H = fmaxf(fmaf(x0, W_emb[d], b_emb[d]) + acc, 0.f);
    float g0 = U1[n * 64 + d] + T1[ti * 64 + d] + D1[di * 64 + d];
    float g1 = U1[n * 64 + 32 + d] + T1[ti * 64 + 32 + d] + D1[di * 64 + 32 + d];
    float gs = fmaxf(g0, 0.f) * W_g2[d] + fmaxf(g1, 0.f) * W_g2[32 + d];
#pragma unroll
    for (int m = 16; m >= 1; m >>= 1) gs += __shfl_xor(gs, m, 64);
    float gate = 1.f / (1.f + __expf(-(gs + b_g2[0])));
    Xs[d][ls] = f2bf(H * gate);
    __syncthreads();
    if (t < 32) {
        short8 v = *(const short8*)&Xs[t][0];
        *(short8*)&XT[((size_t)b * NJ + l * 32 + t) * NN + n0] = v;
    }
    // fused out0: out = b_dif + X @ W_dif[0:32]
    float a0 = b_dif[d];
#pragma unroll 8
    for (int j = 0; j < 32; ++j) a0 = fmaf(bf2f(Xs[j][ls]), W0s[j * 32 + d], a0);
    out[(((size_t)b * LLEN + l) * NN + n) * 32 + d] = a0;
}

// ---------------- K4: MFMA diffusion, BM=128 BN=64 BK=64, XOR-swizzled LDS, dbuf + reg prefetch ----------
// z = s*4 + b; s=0 static (S_bf, no resid), s=1 fwd (adjF, rs), s=2 bwd (adjT, cs)
// D[j,n] = sum_k InT[j,k]*W[k,n] with W[k,n] = support[n,k]
__global__ __launch_bounds__(256) void k_diff3(const ushort* __restrict__ S_bf,
                                               const ushort* __restrict__ adjF,
                                               const ushort* __restrict__ adjT,
                                               const float* __restrict__ rs,
                                               const float* __restrict__ cs,
                                               const ushort* __restrict__ In0,
                                               int in_per_chain,
                                               ushort* __restrict__ Out0) {
    __shared__ __align__(16) ushort As[2][128 * 64];
    __shared__ __align__(16) ushort Ws[2][64 * 64];
    int z = blockIdx.z;
    int s = z >> 2, b = z & 3;
    int j0 = blockIdx.x * 128;
    int n0 = blockIdx.y * 64;
    const size_t ZT = (size_t)BBATCH * NJ * NN;
    const ushort* Wb = (s == 0) ? S_bf
                     : (s == 1) ? adjF + (size_t)b * NN * NN
                                : adjT + (size_t)b * NN * NN;
    const float* deg = (s == 0) ? nullptr : (s == 1 ? rs : cs);
    const ushort* Inb = In0 + (in_per_chain ? (size_t)s * ZT : 0) + (size_t)b * NJ * NN;
    ushort* Outb = Out0 + (size_t)s * ZT + (size_t)b * NJ * NN;

    int t = threadIdx.x;
    // staging: A 128 rows x 8 chunks(16B); thread t -> row t>>1, chunks (t&1)*4 .. +3
    //          W 64 rows x 8 chunks;       thread t -> row t>>2, chunks (t&3)*2 .. +1
    int arow = t >> 1, ac = (t & 1) * 4;
    int wrow = t >> 2, wc = (t & 3) * 2;
    const ushort* pA = Inb + (size_t)(j0 + arow) * NN + ac * 8;
    const ushort* pW = Wb + (size_t)(n0 + wrow) * NN + wc * 8;
    int w = t >> 6, wm = w >> 1, wn = w & 1;     // wave tile: 64j x 32n
    int l = t & 63, lr = l & 15, lg = l >> 4;
    f32x4 acc[4][2];
#pragma unroll
    for (int i = 0; i < 4; ++i)
#pragma unroll
        for (int j = 0; j < 2; ++j) acc[i][j] = (f32x4){0.f, 0.f, 0.f, 0.f};

    short8 ra[4], rw[2];
#pragma unroll
    for (int i = 0; i < 4; ++i) ra[i] = *(const short8*)(pA + i * 8);
#pragma unroll
    for (int i = 0; i < 2; ++i) rw[i] = *(const short8*)(pW + i * 8);
#pragma unroll
    for (int i = 0; i < 4; ++i)
        *(short8*)&As[0][arow * 64 + (((ac + i) ^ (arow & 7)) * 8)] = ra[i];
#pragma unroll
    for (int i = 0; i < 2; ++i)
        *(short8*)&Ws[0][wrow * 64 + (((wc + i) ^ (wrow & 7)) * 8)] = rw[i];
    __syncthreads();

    int cur = 0;
    for (int kt = 0; kt < 16; ++kt) {
        if (kt < 15) {
            const ushort* qA = pA + (size_t)(kt + 1) * 64;
            const ushort* qW = pW + (size_t)(kt + 1) * 64;
#pragma unroll
            for (int i = 0; i < 4; ++i) ra[i] = *(const short8*)(qA + i * 8);
#pragma unroll
            for (int i = 0; i < 2; ++i) rw[i] = *(const short8*)(qW + i * 8);
        }
#pragma unroll
        for (int kk = 0; kk < 2; ++kk) {
            short8 af[4], bf[2];
#pragma unroll
            for (int mf = 0; mf < 4; ++mf) {
                int row = wm * 64 + mf * 16 + lr;
                af[mf] = *(const short8*)&As[cur][row * 64 + (((kk * 4 + lg) ^ (row & 7)) * 8)];
            }
#pragma unroll
            for (int nf = 0; nf < 2; ++nf) {
                int row = wn * 32 + nf * 16 + lr;
                bf[nf] = *(const short8*)&Ws[cur][row * 64 + (((kk * 4 + lg) ^ (row & 7)) * 8)];
            }
#pragma unroll
            for (int mf = 0; mf < 4; ++mf) {
                acc[mf][0] = __builtin_amdgcn_mfma_f32_16x16x32_bf16(af[mf], bf[0], acc[mf][0], 0, 0, 0);
                acc[mf][1] = __builtin_amdgcn_mfma_f32_16x16x32_bf16(af[mf], bf[1], acc[mf][1], 0, 0, 0);
            }
        }
        if (kt < 15) {
#pragma unroll
            for (int i = 0; i < 4; ++i)
                *(short8*)&As[cur ^ 1][arow * 64 + (((ac + i) ^ (arow & 7)) * 8)] = ra[i];
#pragma unroll
            for (int i = 0; i < 2; ++i)
                *(short8*)&Ws[cur ^ 1][wrow * 64 + (((wc + i) ^ (wrow & 7)) * 8)] = rw[i];
        }
        __syncthreads();
        cur ^= 1;
    }
    bool resid = (deg != nullptr);
#pragma unroll
    for (int nf = 0; nf < 2; ++nf) {
        int n_g = n0 + wn * 32 + nf * 16 + lr;
        float scale = 1.f;
        if (resid) scale = 1.f / (deg[b * NN + n_g] + 1.f);
#pragma unroll
        for (int mf = 0; mf < 4; ++mf) {
#pragma unroll
            for (int r = 0; r < 4; ++r) {
                int j_g = j0 + wm * 64 + mf * 16 + lg * 4 + r;
                float v = acc[mf][nf][r];
                if (resid) v += bf2f(Inb[(size_t)j_g * NN + n_g]);
                v *= scale;
                Outb[(size_t)j_g * NN + n_g] = f2bf(v);
            }
        }
    }
}

// ---------------- K5: out += sum over 6 Z tensors of Z @ W_dif[32+c*32 : +32] ----------------
__global__ __launch_bounds__(256) void k_zall(const ushort* __restrict__ Z1,
                                              const ushort* __restrict__ Z2,
                                              const float* __restrict__ W_dif,
                                              float* __restrict__ out) {
    __shared__ float zs[6][32][64];
    __shared__ float wsm[6][32][32];
    const size_t ZT = (size_t)BBATCH * NJ * NN;
    int t = threadIdx.x;
    int n0 = blockIdx.x * 64;
    int l = blockIdx.y;
    int b = blockIdx.z;
    for (int i = t; i < 6144; i += 256) ((float*)wsm)[i] = W_dif[1024 + i];
    {
        int jr = t >> 3, ch = t & 7;
        size_t base = ((size_t)b * NJ + l * 32 + jr) * NN + n0 + ch * 8;
#pragma unroll
        for (int c = 0; c < 6; ++c) {
            const ushort* Zp = ((c & 1) ? Z2 : Z1) + (size_t)(c >> 1) * ZT;
            short8 v = *(const short8*)&Zp[base];
#pragma unroll
            for (int q = 0; q < 8; ++q) zs[c][jr][ch * 8 + q] = bf2f((ushort)v[q]);
        }
    }
    __syncthreads();
    int d = t & 31, nl = t >> 5;
    size_t ob = (((size_t)b * LLEN + l) * NN + n0 + nl) * 32 + d;
    float acc[8];
#pragma unroll
    for (int i = 0; i < 8; ++i) acc[i] = out[ob + (size_t)(8 * i) * 32];
#pragma unroll 2
    for (int c = 0; c < 6; ++c)
        for (int j = 0; j < 32; ++j) {
            float wv = wsm[c][j][d];
#pragma unroll
            for (int i = 0; i < 8; ++i) acc[i] = fmaf(zs[c][j][nl + 8 * i], wv, acc[i]);
        }
#pragma unroll
    for (int i = 0; i < 8; ++i) out[ob + (size_t)(8 * i) * 32] = acc[i];
}

extern "C" void kernel_launch(void* const* d_in, const int* in_sizes, int n_in,
                              void* d_out, int out_size, void* d_ws, size_t ws_size,
                              hipStream_t stream) {
    (void)in_sizes; (void)n_in; (void)out_size; (void)ws_size;
    const float* hist  = (const float*)d_in[0];
    const float* hs    = (const float*)d_in[1];
    const float* adj   = (const float*)d_in[2];
    const float* W_emb = (const float*)d_in[3];
    const float* b_emb = (const float*)d_in[4];
    const float* W_st  = (const float*)d_in[5];
    const float* b_st  = (const float*)d_in[6];
    const float* TiD   = (const float*)d_in[7];
    const float* DiW   = (const float*)d_in[8];
    const float* emb_u = (const float*)d_in[9];
    const float* emb_d = (const float*)d_in[10];
    const float* W_g1  = (const float*)d_in[11];
    const float* b_g1  = (const float*)d_in[12];
    const float* W_g2  = (const float*)d_in[13];
    const float* b_g2  = (const float*)d_in[14];
    const float* W_dif = (const float*)d_in[15];
    const float* b_dif = (const float*)d_in[16];
    float* out = (float*)d_out;

    // ws layout (bytes), total ~39.4 MB (ws_size ~268 MB per fill evidence)
    uint8_t* w8 = (uint8_t*)d_ws;
    ushort* adjF = (ushort*)w8;                      // 8 MB  adj bf16 [b][n][k]
    ushort* adjT = (ushort*)(w8 + 8388608);          // 8 MB  adj^T bf16 [b][n][k]
    ushort* S_bf = (ushort*)(w8 + 16777216);         // 2 MB
    ushort* XT   = (ushort*)(w8 + 18874368);         // 3 MB  [b][384][1024]
    ushort* Z1   = (ushort*)(w8 + 22020096);         // 9 MB  [s][b][384][1024]
    ushort* Z2   = (ushort*)(w8 + 31457280);         // 9 MB
    float*  rs   = (float*)(w8 + 40894464);          // 16 KB
    float*  cs   = (float*)(w8 + 40910848);          // 16 KB (contiguous with rs)
    float*  U1   = (float*)(w8 + 40927232);          // 256 KB
    float*  T1   = (float*)(w8 + 41189376);          // 72 KB
    float*  D1   = (float*)(w8 + 41263104);          // 1.8 KB

    hipMemsetAsync(rs, 0, 2 * BBATCH * NN * sizeof(float), stream);   // rs + cs
    k_adj_pre<<<dim3(16, 16, 4), 256, 0, stream>>>(adj, adjF, adjT, rs, cs);
    k_gate_pre<<<NN + TIDC + DIWC, 64, 0, stream>>>(emb_u, emb_d, W_g1, b_g1, TiD, DiW, U1, T1, D1);
    k_static<<<NN, 256, 0, stream>>>(emb_u, emb_d, S_bf);
    k_xspa<<<6144, 256, 0, stream>>>(hist, hs, W_emb, b_emb, W_st, b_st, U1, T1, D1,
                                     W_g2, b_g2, W_dif, b_dif, XT, out);
    dim3 dgrid(3, 16, 12);
    k_diff3<<<dgrid, 256, 0, stream>>>(S_bf, adjF, adjT, rs, cs, XT, 0, Z1);
    k_diff3<<<dgrid, 256, 0, stream>>>(S_bf, adjF, adjT, rs, cs, Z1, 1, Z2);
    k_zall<<<dim3(16, 12, 4), 256, 0, stream>>>(Z1, Z2, W_dif, out);
}

// Round 6
// 241.170 us; speedup vs baseline: 2.6610x; 1.0425x over previous
//
#include <hip/hip_runtime.h>
#include <hip/hip_bf16.h>
#include <cstdint>

#define NN 1024
#define BBATCH 4
#define LLEN 12
#define NJ 384   // LLEN*32
#define TIDC 288
#define DIWC 7

typedef __attribute__((ext_vector_type(8))) short short8;
typedef __attribute__((ext_vector_type(4))) float f32x4;

__device__ inline ushort f2bf(float f) {
    unsigned u = __float_as_uint(f);
    u += 0x7FFFu + ((u >> 16) & 1u);
    return (ushort)(u >> 16);
}
__device__ inline float bf2f(ushort u) { return __uint_as_float(((unsigned)u) << 16); }

// ---------------- K1: static support S = softmax(relu(emb_d @ emb_u^T), axis=1), bf16 out ----------------
__global__ __launch_bounds__(256) void k_static(const float* __restrict__ emb_u,
                                                const float* __restrict__ emb_d,
                                                ushort* __restrict__ S_bf) {
    int i = blockIdx.x;
    int t = threadIdx.x;
    __shared__ float drow[32];
    __shared__ float red[256];
    if (t < 32) drow[t] = emb_d[i * 32 + t];
    __syncthreads();
    float v[4];
    float lsum = 0.f;
    for (int jj = 0; jj < 4; ++jj) {
        int j = jj * 256 + t;
        const float4* u4 = reinterpret_cast<const float4*>(emb_u + (size_t)j * 32);
        float acc = 0.f;
#pragma unroll
        for (int k4 = 0; k4 < 8; ++k4) {
            float4 u = u4[k4];
            acc += drow[k4 * 4 + 0] * u.x + drow[k4 * 4 + 1] * u.y +
                   drow[k4 * 4 + 2] * u.z + drow[k4 * 4 + 3] * u.w;
        }
        acc = fmaxf(acc, 0.f);
        v[jj] = __expf(acc);
        lsum += v[jj];
    }
    red[t] = lsum;
    __syncthreads();
    for (int s = 128; s > 0; s >>= 1) {
        if (t < s) red[t] += red[t + s];
        __syncthreads();
    }
    float inv = 1.f / red[0];
    for (int jj = 0; jj < 4; ++jj) S_bf[(size_t)i * NN + jj * 256 + t] = f2bf(v[jj] * inv);
}

// ---------------- K2: fused adj preprocessing: adjF bf16, adjT bf16, row sums, col sums ----------------
__global__ __launch_bounds__(256) void k_adj_pre(const float* __restrict__ adj,
                                                 ushort* __restrict__ adjF,
                                                 ushort* __restrict__ adjT,
                                                 float* __restrict__ rs,
                                                 float* __restrict__ cs) {
    __shared__ float tile[64][65];
    int b = blockIdx.z;
    int r0 = blockIdx.y * 64, c0 = blockIdx.x * 64;
    int t = threadIdx.x;
    int col = (t & 15) * 4, rb = t >> 4;
#pragma unroll
    for (int i = 0; i < 4; ++i) {
        int r = rb + i * 16;
        float4 v = *reinterpret_cast<const float4*>(&adj[((size_t)b * NN + r0 + r) * NN + c0 + col]);
        tile[r][col] = v.x; tile[r][col + 1] = v.y; tile[r][col + 2] = v.z; tile[r][col + 3] = v.w;
        unsigned lo = (unsigned)f2bf(v.x) | ((unsigned)f2bf(v.y) << 16);
        unsigned hi = (unsigned)f2bf(v.z) | ((unsigned)f2bf(v.w) << 16);
        *reinterpret_cast<uint2*>(&adjF[((size_t)b * NN + r0 + r) * NN + c0 + col]) = make_uint2(lo, hi);
    }
    __syncthreads();
    {
        int r4 = t >> 2, q4 = t & 3;
        float s1 = 0.f;
#pragma unroll
        for (int c = 0; c < 16; ++c) s1 += tile[r4][q4 * 16 + c];
        s1 += __shfl_xor(s1, 1, 64);
        s1 += __shfl_xor(s1, 2, 64);
        if (q4 == 0) atomicAdd(&rs[b * NN + r0 + r4], s1);
        float s2 = 0.f;
#pragma unroll
        for (int rr = 0; rr < 16; ++rr) s2 += tile[q4 * 16 + rr][r4];
        s2 += __shfl_xor(s2, 1, 64);
        s2 += __shfl_xor(s2, 2, 64);
        if (q4 == 0) atomicAdd(&cs[b * NN + c0 + r4], s2);
    }
    int j = t >> 2, ch = t & 3;
    short8 o0, o1;
#pragma unroll
    for (int q = 0; q < 8; ++q) o0[q] = (short)f2bf(tile[ch * 16 + q][j]);
#pragma unroll
    for (int q = 0; q < 8; ++q) o1[q] = (short)f2bf(tile[ch * 16 + 8 + q][j]);
    size_t orow = ((size_t)b * NN + c0 + j) * NN + r0 + ch * 16;
    *(short8*)&adjT[orow] = o0;
    *(short8*)&adjT[orow + 8] = o1;
}

// ---------------- K0: gate-MLP layer-1 tables + weight transposes ----------------
__global__ __launch_bounds__(64) void k_gate_pre(const float* __restrict__ emb_u,
                                                 const float* __restrict__ emb_d,
                                                 const float* __restrict__ W_g1,
                                                 const float* __restrict__ b_g1,
                                                 const float* __restrict__ TiD,
                                                 const float* __restrict__ DiW,
                                                 const float* __restrict__ W_st,
                                                 const float* __restrict__ W_dif,
                                                 float* __restrict__ U1, float* __restrict__ T1,
                                                 float* __restrict__ D1,
                                                 float* __restrict__ WstT_g,
                                                 float* __restrict__ W0T_g) {
    int r = blockIdx.x;
    int h = threadIdx.x;   // 64
    if (r < NN) {
        float acc = b_g1[h];
        for (int i = 0; i < 32; ++i) acc = fmaf(emb_u[r * 32 + i], W_g1[(20 + i) * 64 + h], acc);
        for (int i = 0; i < 32; ++i) acc = fmaf(emb_d[r * 32 + i], W_g1[(52 + i) * 64 + h], acc);
        U1[r * 64 + h] = acc;
    } else if (r < NN + TIDC) {
        int tt = r - NN;
        float acc = 0.f;
        for (int i = 0; i < 10; ++i) acc = fmaf(TiD[tt * 10 + i], W_g1[i * 64 + h], acc);
        T1[tt * 64 + h] = acc;
    } else if (r < NN + TIDC + DIWC) {
        int dd = r - (NN + TIDC);
        float acc = 0.f;
        for (int i = 0; i < 10; ++i) acc = fmaf(DiW[dd * 10 + i], W_g1[(10 + i) * 64 + h], acc);
        D1[dd * 64 + h] = acc;
    } else if (r == NN + TIDC + DIWC) {
        for (int i = h; i < 32 * 96; i += 64) WstT_g[i] = W_st[(i % 96) * 32 + i / 96];
    } else {
        for (int i = h; i < 32 * 32; i += 64) W0T_g[i] = W_dif[(i % 32) * 32 + i / 32];
    }
}

// ---------------- K3: fused H_st + H + gate + X_spa -> XT bf16 [b][j][n]  AND  out0 ----------------
// block = 64 consecutive n at fixed (b,l); grid (16, 12, 4)
__global__ __launch_bounds__(256) void k_xspa(const float* __restrict__ hist,
                                              const float* __restrict__ hs,
                                              const float* __restrict__ W_emb,
                                              const float* __restrict__ b_emb,
                                              const float* __restrict__ b_st,
                                              const float* __restrict__ U1,
                                              const float* __restrict__ T1,
                                              const float* __restrict__ D1,
                                              const float* __restrict__ W_g2,
                                              const float* __restrict__ b_g2,
                                              const float* __restrict__ b_dif,
                                              const float* __restrict__ WstT_g,
                                              const float* __restrict__ W0T_g,
                                              ushort* __restrict__ XT,
                                              float* __restrict__ out) {
    __shared__ float WstT[32][100];   // [d][k], row pad 100 (16B aligned rows)
    __shared__ float W0T[32][36];     // [d][j]
    __shared__ float hsm[64][96];     // [site][k]
    __shared__ float Hs[64][36];      // [site][d]
    __shared__ float gateL[64];
    __shared__ float histL[192];
    int t = threadIdx.x;
    int n0 = blockIdx.x * 64;
    int l = blockIdx.y;
    int b = blockIdx.z;
    for (int i = t; i < 32 * 96; i += 256) WstT[i / 96][i % 96] = WstT_g[i];
    for (int i = t; i < 32 * 32; i += 256) W0T[i / 32][i % 32] = W0T_g[i];
    if (t < 48)
        *(float4*)&histL[t * 4] =
            *(const float4*)&hist[(((size_t)b * LLEN + l) * NN + n0) * 3 + t * 4];
#pragma unroll
    for (int r = 0; r < 6; ++r) {
        int i = t + 256 * r;          // 0..1535 over (site, chunk4)
        int s = i / 24, c = i % 24;
        float4 v = *(const float4*)&hs[(((size_t)b * NN + n0 + s) * LLEN + l) * 96 + c * 4];
        *(float4*)&hsm[s][c * 4] = v;
    }
    __syncthreads();
    // ---- H phase: thread (d, g) computes 8 sites g*8..g*8+7
    int d = t & 31, g = t >> 5;
    float acc[8];
#pragma unroll
    for (int i = 0; i < 8; ++i) acc[i] = 0.f;
    for (int k4 = 0; k4 < 24; ++k4) {
        float4 w = *(const float4*)&WstT[d][k4 * 4];
#pragma unroll
        for (int i = 0; i < 8; ++i) {
            float4 h4 = *(const float4*)&hsm[g * 8 + i][k4 * 4];
            acc[i] = fmaf(h4.x, w.x, acc[i]);
            acc[i] = fmaf(h4.y, w.y, acc[i]);
            acc[i] = fmaf(h4.z, w.z, acc[i]);
            acc[i] = fmaf(h4.w, w.w, acc[i]);
        }
    }
    {
        float we = W_emb[d], be = b_emb[d], bst = b_st[d];
#pragma unroll
        for (int i = 0; i < 8; ++i) {
            int s = g * 8 + i;
            Hs[s][d] = fmaxf(fmaf(histL[s * 3], we, be) + bst + acc[i], 0.f);
        }
    }
    __syncthreads();
    // ---- gate phase: 64 sites x 4 lanes
    {
        int s = t >> 2, q = t & 3;
        int n = n0 + s;
        float x1 = histL[s * 3 + 1];
        float x2 = histL[s * 3 + 2] * (1.f / 7.f);
        int ti = (int)(x1 * 288.f); ti = ti < 0 ? 0 : (ti > 287 ? 287 : ti);
        int di = (int)(x2 * 7.f);   di = di < 0 ? 0 : (di > 6 ? 6 : di);
        const float* up = U1 + n * 64 + q * 16;
        const float* tp = T1 + ti * 64 + q * 16;
        const float* dp = D1 + di * 64 + q * 16;
        const float* wp = W_g2 + q * 16;
        float a = 0.f;
#pragma unroll
        for (int h = 0; h < 16; ++h)
            a = fmaf(fmaxf(up[h] + tp[h] + dp[h], 0.f), wp[h], a);
        a += __shfl_xor(a, 1, 64);
        a += __shfl_xor(a, 2, 64);
        if (q == 0) gateL[s] = 1.f / (1.f + __expf(-(a + b_g2[0])));
    }
    __syncthreads();
    // ---- out0 phase: out = b_dif + gate * (Hs @ W0)
    {
        float bd = b_dif[d];
#pragma unroll
        for (int i = 0; i < 8; ++i) {
            int s = g * 8 + i;
            float a = 0.f;
#pragma unroll
            for (int j4 = 0; j4 < 8; ++j4) {
                float4 w = *(const float4*)&W0T[d][j4 * 4];
                float4 h4 = *(const float4*)&Hs[s][j4 * 4];
                a = fmaf(h4.x, w.x, a); a = fmaf(h4.y, w.y, a);
                a = fmaf(h4.z, w.z, a); a = fmaf(h4.w, w.w, a);
            }
            out[(((size_t)b * LLEN + l) * NN + n0 + s) * 32 + d] = fmaf(gateL[s], a, bd);
        }
    }
    // ---- XT write: thread (dd = t>>3, c = t&7) -> 8 contiguous n
    {
        int dd = t >> 3, c = t & 7;
        short8 v;
#pragma unroll
        for (int i = 0; i < 8; ++i) {
            int s = c * 8 + i;
            v[i] = (short)f2bf(Hs[s][dd] * gateL[s]);
        }
        *(short8*)&XT[((size_t)b * NJ + l * 32 + dd) * NN + n0 + c * 8] = v;
    }
}

// ---------------- K4: MFMA diffusion, BM=128 BN=64 BK=64, depth-2 reg pipeline, XCD swizzle ----------
// zz = s*4 + b; s=0 static (S_bf, no resid), s=1 fwd (adjF, rs), s=2 bwd (adjT, cs)
#define DIFF_LOAD(ra, rw, kt)                                          \
    {                                                                  \
        const ushort* qA = pA + (size_t)(kt) * 64;                     \
        const ushort* qW = pW + (size_t)(kt) * 64;                     \
        _Pragma("unroll") for (int i = 0; i < 4; ++i)                  \
            ra[i] = *(const short8*)(qA + i * 8);                      \
        _Pragma("unroll") for (int i = 0; i < 2; ++i)                  \
            rw[i] = *(const short8*)(qW + i * 8);                      \
    }
#define DIFF_WRITE(buf, ra, rw)                                        \
    {                                                                  \
        _Pragma("unroll") for (int i = 0; i < 4; ++i)                  \
            *(short8*)&As[buf][arow * 64 + (((ac + i) ^ (arow & 7)) * 8)] = ra[i]; \
        _Pragma("unroll") for (int i = 0; i < 2; ++i)                  \
            *(short8*)&Ws[buf][wrow * 64 + (((wc + i) ^ (wrow & 7)) * 8)] = rw[i]; \
    }
#define DIFF_COMPUTE(buf)                                              \
    {                                                                  \
        _Pragma("unroll") for (int kk = 0; kk < 2; ++kk) {             \
            short8 af[4], bff[2];                                      \
            _Pragma("unroll") for (int mf = 0; mf < 4; ++mf) {         \
                int row = wm * 64 + mf * 16 + lr;                      \
                af[mf] = *(const short8*)&As[buf][row * 64 + (((kk * 4 + lg) ^ (row & 7)) * 8)]; \
            }                                                          \
            _Pragma("unroll") for (int nf = 0; nf < 2; ++nf) {         \
                int row = wn * 32 + nf * 16 + lr;                      \
                bff[nf] = *(const short8*)&Ws[buf][row * 64 + (((kk * 4 + lg) ^ (row & 7)) * 8)]; \
            }                                                          \
            _Pragma("unroll") for (int mf = 0; mf < 4; ++mf) {         \
                acc[mf][0] = __builtin_amdgcn_mfma_f32_16x16x32_bf16(af[mf], bff[0], acc[mf][0], 0, 0, 0); \
                acc[mf][1] = __builtin_amdgcn_mfma_f32_16x16x32_bf16(af[mf], bff[1], acc[mf][1], 0, 0, 0); \
            }                                                          \
        }                                                              \
    }

__global__ __launch_bounds__(256) void k_diff3(const ushort* __restrict__ S_bf,
                                               const ushort* __restrict__ adjF,
                                               const ushort* __restrict__ adjT,
                                               const float* __restrict__ rs,
                                               const float* __restrict__ cs,
                                               const ushort* __restrict__ In0,
                                               int in_per_chain,
                                               ushort* __restrict__ Out0) {
    __shared__ __align__(16) ushort As[2][128 * 64];
    __shared__ __align__(16) ushort Ws[2][64 * 64];
    // bijective XCD swizzle over 576 blocks (72 per XCD)
    int bid = blockIdx.x + 3 * blockIdx.y + 48 * blockIdx.z;
    int swz = (bid & 7) * 72 + (bid >> 3);
    int xx = swz % 3, yy = (swz / 3) % 16, zz = swz / 48;
    int s = zz >> 2, b = zz & 3;
    int j0 = xx * 128;
    int n0 = yy * 64;
    const size_t ZT = (size_t)BBATCH * NJ * NN;
    const ushort* Wb = (s == 0) ? S_bf
                     : (s == 1) ? adjF + (size_t)b * NN * NN
                                : adjT + (size_t)b * NN * NN;
    const float* deg = (s == 0) ? nullptr : (s == 1 ? rs : cs);
    const ushort* Inb = In0 + (in_per_chain ? (size_t)s * ZT : 0) + (size_t)b * NJ * NN;
    ushort* Outb = Out0 + (size_t)s * ZT + (size_t)b * NJ * NN;

    int t = threadIdx.x;
    int arow = t >> 1, ac = (t & 1) * 4;
    int wrow = t >> 2, wc = (t & 3) * 2;
    const ushort* pA = Inb + (size_t)(j0 + arow) * NN + ac * 8;
    const ushort* pW = Wb + (size_t)(n0 + wrow) * NN + wc * 8;
    int w = t >> 6, wm = w >> 1, wn = w & 1;     // wave tile: 64j x 32n
    int l = t & 63, lr = l & 15, lg = l >> 4;
    f32x4 acc[4][2];
#pragma unroll
    for (int i = 0; i < 4; ++i)
#pragma unroll
        for (int j = 0; j < 2; ++j) acc[i][j] = (f32x4){0.f, 0.f, 0.f, 0.f};

    short8 raA[4], rwA[2], raB[4], rwB[2];
    DIFF_LOAD(raA, rwA, 0);
    DIFF_LOAD(raB, rwB, 1);
    DIFF_WRITE(0, raA, rwA);
    __syncthreads();
    int cur = 0;
#pragma unroll 1
    for (int kt2 = 0; kt2 < 16; kt2 += 2) {
        // even phase: LDS[cur] = kt2; B regs hold kt2+1
        if (kt2 + 2 < 16) DIFF_LOAD(raA, rwA, kt2 + 2);
        DIFF_COMPUTE(cur);
        DIFF_WRITE(cur ^ 1, raB, rwB);
        __syncthreads();
        cur ^= 1;
        // odd phase: LDS[cur] = kt2+1; A regs hold kt2+2
        if (kt2 + 3 < 16) DIFF_LOAD(raB, rwB, kt2 + 3);
        DIFF_COMPUTE(cur);
        if (kt2 + 2 < 16) DIFF_WRITE(cur ^ 1, raA, rwA);
        __syncthreads();
        cur ^= 1;
    }
    bool resid = (deg != nullptr);
#pragma unroll
    for (int nf = 0; nf < 2; ++nf) {
        int n_g = n0 + wn * 32 + nf * 16 + lr;
        float scale = 1.f;
        if (resid) scale = 1.f / (deg[b * NN + n_g] + 1.f);
#pragma unroll
        for (int mf = 0; mf < 4; ++mf) {
#pragma unroll
            for (int r = 0; r < 4; ++r) {
                int j_g = j0 + wm * 64 + mf * 16 + lg * 4 + r;
                float v = acc[mf][nf][r];
                if (resid) v += bf2f(Inb[(size_t)j_g * NN + n_g]);
                v *= scale;
                Outb[(size_t)j_g * NN + n_g] = f2bf(v);
            }
        }
    }
}

// ---------------- K5: out += sum over 6 Z tensors of Z @ W_dif[32+c*32 : +32] ----------------
__global__ __launch_bounds__(256) void k_zall(const ushort* __restrict__ Z1,
                                              const ushort* __restrict__ Z2,
                                              const float* __restrict__ W_dif,
                                              float* __restrict__ out) {
    __shared__ float zs[6][32][64];
    __shared__ float wsm[6][32][32];
    const size_t ZT = (size_t)BBATCH * NJ * NN;
    int t = threadIdx.x;
    int n0 = blockIdx.x * 64;
    int l = blockIdx.y;
    int b = blockIdx.z;
    for (int i = t; i < 6144; i += 256) ((float*)wsm)[i] = W_dif[1024 + i];
    {
        int jr = t >> 3, ch = t & 7;
        size_t base = ((size_t)b * NJ + l * 32 + jr) * NN + n0 + ch * 8;
#pragma unroll
        for (int c = 0; c < 6; ++c) {
            const ushort* Zp = ((c & 1) ? Z2 : Z1) + (size_t)(c >> 1) * ZT;
            short8 v = *(const short8*)&Zp[base];
#pragma unroll
            for (int q = 0; q < 8; ++q) zs[c][jr][ch * 8 + q] = bf2f((ushort)v[q]);
        }
    }
    __syncthreads();
    int d = t & 31, nl = t >> 5;
    size_t ob = (((size_t)b * LLEN + l) * NN + n0 + nl) * 32 + d;
    float acc[8];
#pragma unroll
    for (int i = 0; i < 8; ++i) acc[i] = out[ob + (size_t)(8 * i) * 32];
#pragma unroll 2
    for (int c = 0; c < 6; ++c)
        for (int j = 0; j < 32; ++j) {
            float wv = wsm[c][j][d];
#pragma unroll
            for (int i = 0; i < 8; ++i) acc[i] = fmaf(zs[c][j][nl + 8 * i], wv, acc[i]);
        }
#pragma unroll
    for (int i = 0; i < 8; ++i) out[ob + (size_t)(8 * i) * 32] = acc[i];
}

extern "C" void kernel_launch(void* const* d_in, const int* in_sizes, int n_in,
                              void* d_out, int out_size, void* d_ws, size_t ws_size,
                              hipStream_t stream) {
    (void)in_sizes; (void)n_in; (void)out_size; (void)ws_size;
    const float* hist  = (const float*)d_in[0];
    const float* hs    = (const float*)d_in[1];
    const float* adj   = (const float*)d_in[2];
    const float* W_emb = (const float*)d_in[3];
    const float* b_emb = (const float*)d_in[4];
    const float* W_st  = (const float*)d_in[5];
    const float* b_st  = (const float*)d_in[6];
    const float* TiD   = (const float*)d_in[7];
    const float* DiW   = (const float*)d_in[8];
    const float* emb_u = (const float*)d_in[9];
    const float* emb_d = (const float*)d_in[10];
    const float* W_g1  = (const float*)d_in[11];
    const float* b_g1  = (const float*)d_in[12];
    const float* W_g2  = (const float*)d_in[13];
    const float* b_g2  = (const float*)d_in[14];
    const float* W_dif = (const float*)d_in[15];
    const float* b_dif = (const float*)d_in[16];
    float* out = (float*)d_out;

    // ws layout (bytes), total ~39.4 MB (ws_size ~268 MB per fill evidence)
    uint8_t* w8 = (uint8_t*)d_ws;
    ushort* adjF = (ushort*)w8;                      // 8 MB  adj bf16 [b][n][k]
    ushort* adjT = (ushort*)(w8 + 8388608);          // 8 MB  adj^T bf16 [b][n][k]
    ushort* S_bf = (ushort*)(w8 + 16777216);         // 2 MB
    ushort* XT   = (ushort*)(w8 + 18874368);         // 3 MB  [b][384][1024]
    ushort* Z1   = (ushort*)(w8 + 22020096);         // 9 MB  [s][b][384][1024]
    ushort* Z2   = (ushort*)(w8 + 31457280);         // 9 MB
    float*  rs   = (float*)(w8 + 40894464);          // 16 KB
    float*  cs   = (float*)(w8 + 40910848);          // 16 KB (contiguous with rs)
    float*  U1   = (float*)(w8 + 40927232);          // 256 KB
    float*  T1   = (float*)(w8 + 41189376);          // 72 KB
    float*  D1   = (float*)(w8 + 41263104);          // 1.8 KB
    float*  WstT = (float*)(w8 + 41264896);          // 12 KB
    float*  W0T  = (float*)(w8 + 41277184);          // 4 KB

    hipMemsetAsync(rs, 0, 2 * BBATCH * NN * sizeof(float), stream);   // rs + cs
    k_adj_pre<<<dim3(16, 16, 4), 256, 0, stream>>>(adj, adjF, adjT, rs, cs);
    k_gate_pre<<<NN + TIDC + DIWC + 2, 64, 0, stream>>>(emb_u, emb_d, W_g1, b_g1, TiD, DiW,
                                                        W_st, W_dif, U1, T1, D1, WstT, W0T);
    k_static<<<NN, 256, 0, stream>>>(emb_u, emb_d, S_bf);
    k_xspa<<<dim3(16, 12, 4), 256, 0, stream>>>(hist, hs, W_emb, b_emb, b_st, U1, T1, D1,
                                                W_g2, b_g2, b_dif, WstT, W0T, XT, out);
    dim3 dgrid(3, 16, 12);
    k_diff3<<<dgrid, 256, 0, stream>>>(S_bf, adjF, adjT, rs, cs, XT, 0, Z1);
    k_diff3<<<dgrid, 256, 0, stream>>>(S_bf, adjF, adjT, rs, cs, Z1, 1, Z2);
    k_zall<<<dim3(16, 12, 4), 256, 0, stream>>>(Z1, Z2, W_dif, out);
}

// Round 9
// 211.538 us; speedup vs baseline: 3.0337x; 1.1401x over previous
//
#include <hip/hip_runtime.h>
#include <hip/hip_bf16.h>
#include <cstdint>

#define NN 1024
#define BBATCH 4
#define LLEN 12
#define NJ 384   // LLEN*32
#define TIDC 288
#define DIWC 7

typedef __attribute__((ext_vector_type(8))) short short8;
typedef __attribute__((ext_vector_type(4))) float f32x4;

__device__ inline ushort f2bf(float f) {
    unsigned u = __float_as_uint(f);
    u += 0x7FFFu + ((u >> 16) & 1u);
    return (ushort)(u >> 16);
}
__device__ inline float bf2f(ushort u) { return __uint_as_float(((unsigned)u) << 16); }

// ---------------- K1: static support S = softmax(relu(emb_d @ emb_u^T), axis=1), bf16 out ----------------
__global__ __launch_bounds__(256) void k_static(const float* __restrict__ emb_u,
                                                const float* __restrict__ emb_d,
                                                ushort* __restrict__ S_bf) {
    int i = blockIdx.x;
    int t = threadIdx.x;
    __shared__ float drow[32];
    __shared__ float red[256];
    if (t < 32) drow[t] = emb_d[i * 32 + t];
    __syncthreads();
    float v[4];
    float lsum = 0.f;
    for (int jj = 0; jj < 4; ++jj) {
        int j = jj * 256 + t;
        const float4* u4 = reinterpret_cast<const float4*>(emb_u + (size_t)j * 32);
        float acc = 0.f;
#pragma unroll
        for (int k4 = 0; k4 < 8; ++k4) {
            float4 u = u4[k4];
            acc += drow[k4 * 4 + 0] * u.x + drow[k4 * 4 + 1] * u.y +
                   drow[k4 * 4 + 2] * u.z + drow[k4 * 4 + 3] * u.w;
        }
        acc = fmaxf(acc, 0.f);
        v[jj] = __expf(acc);
        lsum += v[jj];
    }
    red[t] = lsum;
    __syncthreads();
    for (int s = 128; s > 0; s >>= 1) {
        if (t < s) red[t] += red[t + s];
        __syncthreads();
    }
    float inv = 1.f / red[0];
    for (int jj = 0; jj < 4; ++jj) S_bf[(size_t)i * NN + jj * 256 + t] = f2bf(v[jj] * inv);
}

// ---------------- K2: fused adj preprocessing: adjF bf16, adjT bf16, row sums, col sums ----------------
__global__ __launch_bounds__(256) void k_adj_pre(const float* __restrict__ adj,
                                                 ushort* __restrict__ adjF,
                                                 ushort* __restrict__ adjT,
                                                 float* __restrict__ rs,
                                                 float* __restrict__ cs) {
    __shared__ float tile[64][65];
    int b = blockIdx.z;
    int r0 = blockIdx.y * 64, c0 = blockIdx.x * 64;
    int t = threadIdx.x;
    int col = (t & 15) * 4, rb = t >> 4;
#pragma unroll
    for (int i = 0; i < 4; ++i) {
        int r = rb + i * 16;
        float4 v = *reinterpret_cast<const float4*>(&adj[((size_t)b * NN + r0 + r) * NN + c0 + col]);
        tile[r][col] = v.x; tile[r][col + 1] = v.y; tile[r][col + 2] = v.z; tile[r][col + 3] = v.w;
        unsigned lo = (unsigned)f2bf(v.x) | ((unsigned)f2bf(v.y) << 16);
        unsigned hi = (unsigned)f2bf(v.z) | ((unsigned)f2bf(v.w) << 16);
        *reinterpret_cast<uint2*>(&adjF[((size_t)b * NN + r0 + r) * NN + c0 + col]) = make_uint2(lo, hi);
    }
    __syncthreads();
    {
        int r4 = t >> 2, q4 = t & 3;
        float s1 = 0.f;
#pragma unroll
        for (int c = 0; c < 16; ++c) s1 += tile[r4][q4 * 16 + c];
        s1 += __shfl_xor(s1, 1, 64);
        s1 += __shfl_xor(s1, 2, 64);
        if (q4 == 0) atomicAdd(&rs[b * NN + r0 + r4], s1);
        float s2 = 0.f;
#pragma unroll
        for (int rr = 0; rr < 16; ++rr) s2 += tile[q4 * 16 + rr][r4];
        s2 += __shfl_xor(s2, 1, 64);
        s2 += __shfl_xor(s2, 2, 64);
        if (q4 == 0) atomicAdd(&cs[b * NN + c0 + r4], s2);
    }
    int j = t >> 2, ch = t & 3;
    short8 o0, o1;
#pragma unroll
    for (int q = 0; q < 8; ++q) o0[q] = (short)f2bf(tile[ch * 16 + q][j]);
#pragma unroll
    for (int q = 0; q < 8; ++q) o1[q] = (short)f2bf(tile[ch * 16 + 8 + q][j]);
    size_t orow = ((size_t)b * NN + c0 + j) * NN + r0 + ch * 16;
    *(short8*)&adjT[orow] = o0;
    *(short8*)&adjT[orow + 8] = o1;
}

// ---------------- K0: gate-MLP layer-1 tables + bf16 weight transposes ----------------
__global__ __launch_bounds__(64) void k_gate_pre(const float* __restrict__ emb_u,
                                                 const float* __restrict__ emb_d,
                                                 const float* __restrict__ W_g1,
                                                 const float* __restrict__ b_g1,
                                                 const float* __restrict__ TiD,
                                                 const float* __restrict__ DiW,
                                                 const float* __restrict__ W_st,
                                                 const float* __restrict__ W_dif,
                                                 float* __restrict__ U1, float* __restrict__ T1,
                                                 float* __restrict__ D1,
                                                 ushort* __restrict__ WstT_bf,
                                                 ushort* __restrict__ WdT_bf) {
    int r = blockIdx.x;
    int h = threadIdx.x;   // 64
    if (r < NN) {
        float acc = b_g1[h];
        for (int i = 0; i < 32; ++i) acc = fmaf(emb_u[r * 32 + i], W_g1[(20 + i) * 64 + h], acc);
        for (int i = 0; i < 32; ++i) acc = fmaf(emb_d[r * 32 + i], W_g1[(52 + i) * 64 + h], acc);
        U1[r * 64 + h] = acc;
    } else if (r < NN + TIDC) {
        int tt = r - NN;
        float acc = 0.f;
        for (int i = 0; i < 10; ++i) acc = fmaf(TiD[tt * 10 + i], W_g1[i * 64 + h], acc);
        T1[tt * 64 + h] = acc;
    } else if (r < NN + TIDC + DIWC) {
        int dd = r - (NN + TIDC);
        float acc = 0.f;
        for (int i = 0; i < 10; ++i) acc = fmaf(DiW[dd * 10 + i], W_g1[(10 + i) * 64 + h], acc);
        D1[dd * 64 + h] = acc;
    } else if (r == NN + TIDC + DIWC) {
        // WstT_bf[d][k] = bf16(W_st[k][d]), 32x96
        for (int i = h; i < 32 * 96; i += 64) WstT_bf[i] = f2bf(W_st[(i % 96) * 32 + i / 96]);
    } else {
        // WdT_bf[d][k] = bf16(W_dif[k][d]), 32x224
        for (int i = h; i < 32 * 224; i += 64) WdT_bf[i] = f2bf(W_dif[(i % 224) * 32 + i / 224]);
    }
}

// ---------------- K3: fused H_st(MFMA) + H + gate + X_spa -> XT bf16 [b][j][n]  AND  out0(MFMA) ----------------
// block = 64 consecutive n at fixed (b,l); grid (16, 12, 4); 4 waves x 16 sites
__global__ __launch_bounds__(256) void k_xspa(const float* __restrict__ hist,
                                              const float* __restrict__ hs,
                                              const float* __restrict__ W_emb,
                                              const float* __restrict__ b_emb,
                                              const float* __restrict__ b_st,
                                              const float* __restrict__ U1,
                                              const float* __restrict__ T1,
                                              const float* __restrict__ D1,
                                              const float* __restrict__ W_g2,
                                              const float* __restrict__ b_g2,
                                              const float* __restrict__ b_dif,
                                              const ushort* __restrict__ WstT_bf,
                                              const ushort* __restrict__ WdT_bf,
                                              ushort* __restrict__ XT,
                                              float* __restrict__ out) {
    __shared__ __align__(16) ushort hsm[64][104];    // [site][k<96], bf16
    __shared__ __align__(16) ushort Wst_s[32][104];  // [d][k<96]
    __shared__ __align__(16) ushort Hs_bf[64][40];   // [site][d<32]
    __shared__ __align__(16) ushort W0_s[32][40];    // [dout][j<32]
    __shared__ float gateL[64];
    __shared__ float histL[192];
    int t = threadIdx.x;
    int n0 = blockIdx.x * 64;
    int l = blockIdx.y;
    int b = blockIdx.z;
    for (int i = t; i < 384; i += 256) {
        int d = i / 12, c = i % 12;
        *(short8*)&Wst_s[d][c * 8] = *(const short8*)&WstT_bf[d * 96 + c * 8];
    }
    if (t < 128) {
        int d = t >> 2, c = t & 3;
        *(short8*)&W0_s[d][c * 8] = *(const short8*)&WdT_bf[d * 224 + c * 8];
    }
    if (t < 48)
        *(float4*)&histL[t * 4] =
            *(const float4*)&hist[(((size_t)b * LLEN + l) * NN + n0) * 3 + t * 4];
#pragma unroll
    for (int rr = 0; rr < 6; ++rr) {
        int i = t + 256 * rr;              // 0..1535 over (site, float4-chunk)
        int s = i / 24, c = i % 24;
        float4 v = *(const float4*)&hs[(((size_t)b * NN + n0 + s) * LLEN + l) * 96 + c * 4];
        ushort4 u;
        u.x = f2bf(v.x); u.y = f2bf(v.y); u.z = f2bf(v.z); u.w = f2bf(v.w);
        *(ushort4*)&hsm[s][c * 4] = u;
    }
    __syncthreads();
    // ---- gate phase: 64 sites x 4 lanes
    {
        int s = t >> 2, q = t & 3;
        int n = n0 + s;
        float x1 = histL[s * 3 + 1];
        float x2 = histL[s * 3 + 2] * (1.f / 7.f);
        int ti = (int)(x1 * 288.f); ti = ti < 0 ? 0 : (ti > 287 ? 287 : ti);
        int di = (int)(x2 * 7.f);   di = di < 0 ? 0 : (di > 6 ? 6 : di);
        const float* up = U1 + n * 64 + q * 16;
        const float* tp = T1 + ti * 64 + q * 16;
        const float* dp = D1 + di * 64 + q * 16;
        const float* wp = W_g2 + q * 16;
        float a = 0.f;
#pragma unroll
        for (int hh = 0; hh < 16; ++hh)
            a = fmaf(fmaxf(up[hh] + tp[hh] + dp[hh], 0.f), wp[hh], a);
        a += __shfl_xor(a, 1, 64);
        a += __shfl_xor(a, 2, 64);
        if (q == 0) gateL[s] = 1.f / (1.f + __expf(-(a + b_g2[0])));
    }
    // ---- MFMA H_st: M=64 sites (4 waves x 16), N=32 d, K=96
    int w = t >> 6, l6 = t & 63, lr = l6 & 15, lg = l6 >> 4;
    f32x4 hacc[2];
    hacc[0] = (f32x4){0.f, 0.f, 0.f, 0.f};
    hacc[1] = (f32x4){0.f, 0.f, 0.f, 0.f};
#pragma unroll
    for (int kc = 0; kc < 3; ++kc) {
        short8 a = *(const short8*)&hsm[w * 16 + lr][kc * 32 + lg * 8];
        short8 b0 = *(const short8*)&Wst_s[lr][kc * 32 + lg * 8];
        short8 b1 = *(const short8*)&Wst_s[16 + lr][kc * 32 + lg * 8];
        hacc[0] = __builtin_amdgcn_mfma_f32_16x16x32_bf16(a, b0, hacc[0], 0, 0, 0);
        hacc[1] = __builtin_amdgcn_mfma_f32_16x16x32_bf16(a, b1, hacc[1], 0, 0, 0);
    }
    // epilogue: H = relu(W_emb*x0 + b_emb + b_st + H_st) -> Hs_bf
#pragma unroll
    for (int h = 0; h < 2; ++h) {
        int d = h * 16 + lr;
        float we = W_emb[d];
        float bb = b_emb[d] + b_st[d];
#pragma unroll
        for (int r = 0; r < 4; ++r) {
            int s = w * 16 + lg * 4 + r;
            float v = fmaxf(fmaf(histL[s * 3], we, bb) + hacc[h][r], 0.f);
            Hs_bf[s][d] = f2bf(v);
        }
    }
    __syncthreads();
    // ---- MFMA out0: out = b_dif + gate * (H @ W_dif[0:32]), K=32
    f32x4 oacc[2];
    oacc[0] = (f32x4){0.f, 0.f, 0.f, 0.f};
    oacc[1] = (f32x4){0.f, 0.f, 0.f, 0.f};
    {
        short8 a = *(const short8*)&Hs_bf[w * 16 + lr][lg * 8];
        short8 b0 = *(const short8*)&W0_s[lr][lg * 8];
        short8 b1 = *(const short8*)&W0_s[16 + lr][lg * 8];
        oacc[0] = __builtin_amdgcn_mfma_f32_16x16x32_bf16(a, b0, oacc[0], 0, 0, 0);
        oacc[1] = __builtin_amdgcn_mfma_f32_16x16x32_bf16(a, b1, oacc[1], 0, 0, 0);
    }
#pragma unroll
    for (int h = 0; h < 2; ++h) {
        int d = h * 16 + lr;
        float bd = b_dif[d];
#pragma unroll
        for (int r = 0; r < 4; ++r) {
            int s = w * 16 + lg * 4 + r;
            out[(((size_t)b * LLEN + l) * NN + n0 + s) * 32 + d] = fmaf(gateL[s], oacc[h][r], bd);
        }
    }
    // ---- XT write: thread (dd = t>>3, c = t&7) -> 8 contiguous n
    {
        int dd = t >> 3, c = t & 7;
        short8 v;
#pragma unroll
        for (int i = 0; i < 8; ++i) {
            int s = c * 8 + i;
            v[i] = (short)f2bf(bf2f(Hs_bf[s][dd]) * gateL[s]);
        }
        *(short8*)&XT[((size_t)b * NJ + l * 32 + dd) * NN + n0 + c * 8] = v;
    }
}

// ---------------- K4: MFMA diffusion, BM=128 BN=64 BK=64, depth-2 reg pipeline, locality swizzle ----------
#define DIFF_LOAD(ra, rw, kt)                                          \
    {                                                                  \
        const ushort* qA = pA + (size_t)(kt) * 64;                     \
        const ushort* qW = pW + (size_t)(kt) * 64;                     \
        _Pragma("unroll") for (int i = 0; i < 4; ++i)                  \
            ra[i] = *(const short8*)(qA + i * 8);                      \
        _Pragma("unroll") for (int i = 0; i < 2; ++i)                  \
            rw[i] = *(const short8*)(qW + i * 8);                      \
    }
#define DIFF_WRITE(buf, ra, rw)                                        \
    {                                                                  \
        _Pragma("unroll") for (int i = 0; i < 4; ++i)                  \
            *(short8*)&As[buf][arow * 64 + (((ac + i) ^ (arow & 7)) * 8)] = ra[i]; \
        _Pragma("unroll") for (int i = 0; i < 2; ++i)                  \
            *(short8*)&Ws[buf][wrow * 64 + (((wc + i) ^ (wrow & 7)) * 8)] = rw[i]; \
    }
#define DIFF_COMPUTE(buf)                                              \
    {                                                                  \
        _Pragma("unroll") for (int kk = 0; kk < 2; ++kk) {             \
            short8 af[4], bff[2];                                      \
            _Pragma("unroll") for (int mf = 0; mf < 4; ++mf) {         \
                int row = wm * 64 + mf * 16 + lr;                      \
                af[mf] = *(const short8*)&As[buf][row * 64 + (((kk * 4 + lg) ^ (row & 7)) * 8)]; \
            }                                                          \
            _Pragma("unroll") for (int nf = 0; nf < 2; ++nf) {         \
                int row = wn * 32 + nf * 16 + lr;                      \
                bff[nf] = *(const short8*)&Ws[buf][row * 64 + (((kk * 4 + lg) ^ (row & 7)) * 8)]; \
            }                                                          \
            _Pragma("unroll") for (int mf = 0; mf < 4; ++mf) {         \
                acc[mf][0] = __builtin_amdgcn_mfma_f32_16x16x32_bf16(af[mf], bff[0], acc[mf][0], 0, 0, 0); \
                acc[mf][1] = __builtin_amdgcn_mfma_f32_16x16x32_bf16(af[mf], bff[1], acc[mf][1], 0, 0, 0); \
            }                                                          \
        }                                                              \
    }

__global__ __launch_bounds__(256) void k_diff3(const ushort* __restrict__ S_bf,
                                               const ushort* __restrict__ adjF,
                                               const ushort* __restrict__ adjT,
                                               const float* __restrict__ rs,
                                               const float* __restrict__ cs,
                                               const ushort* __restrict__ In0,
                                               int in_per_chain,
                                               ushort* __restrict__ Out0) {
    __shared__ __align__(16) ushort As[2][128 * 64];
    __shared__ __align__(16) ushort Ws[2][64 * 64];
    // bijective XCD swizzle over 576 blocks (72 per XCD); decode y-fastest within (x,z)
    int bid = blockIdx.x + 3 * blockIdx.y + 48 * blockIdx.z;
    int swz = (bid & 7) * 72 + (bid >> 3);
    int zz = swz / 48;
    int rem = swz % 48;
    int xx = rem >> 4, yy = rem & 15;
    int s = zz >> 2, b = zz & 3;
    int j0 = xx * 128;
    int n0 = yy * 64;
    const size_t ZT = (size_t)BBATCH * NJ * NN;
    const ushort* Wb = (s == 0) ? S_bf
                     : (s == 1) ? adjF + (size_t)b * NN * NN
                                : adjT + (size_t)b * NN * NN;
    const float* deg = (s == 0) ? nullptr : (s == 1 ? rs : cs);
    const ushort* Inb = In0 + (in_per_chain ? (size_t)s * ZT : 0) + (size_t)b * NJ * NN;
    ushort* Outb = Out0 + (size_t)s * ZT + (size_t)b * NJ * NN;

    int t = threadIdx.x;
    int arow = t >> 1, ac = (t & 1) * 4;
    int wrow = t >> 2, wc = (t & 3) * 2;
    const ushort* pA = Inb + (size_t)(j0 + arow) * NN + ac * 8;
    const ushort* pW = Wb + (size_t)(n0 + wrow) * NN + wc * 8;
    int w = t >> 6, wm = w >> 1, wn = w & 1;     // wave tile: 64j x 32n
    int l = t & 63, lr = l & 15, lg = l >> 4;
    f32x4 acc[4][2];
#pragma unroll
    for (int i = 0; i < 4; ++i)
#pragma unroll
        for (int j = 0; j < 2; ++j) acc[i][j] = (f32x4){0.f, 0.f, 0.f, 0.f};

    short8 raA[4], rwA[2], raB[4], rwB[2];
    DIFF_LOAD(raA, rwA, 0);
    DIFF_LOAD(raB, rwB, 1);
    DIFF_WRITE(0, raA, rwA);
    __syncthreads();
    int cur = 0;
#pragma unroll 1
    for (int kt2 = 0; kt2 < 16; kt2 += 2) {
        if (kt2 + 2 < 16) DIFF_LOAD(raA, rwA, kt2 + 2);
        DIFF_COMPUTE(cur);
        DIFF_WRITE(cur ^ 1, raB, rwB);
        __syncthreads();
        cur ^= 1;
        if (kt2 + 3 < 16) DIFF_LOAD(raB, rwB, kt2 + 3);
        DIFF_COMPUTE(cur);
        if (kt2 + 2 < 16) DIFF_WRITE(cur ^ 1, raA, rwA);
        __syncthreads();
        cur ^= 1;
    }
    bool resid = (deg != nullptr);
#pragma unroll
    for (int nf = 0; nf < 2; ++nf) {
        int n_g = n0 + wn * 32 + nf * 16 + lr;
        float scale = 1.f;
        if (resid) scale = 1.f / (deg[b * NN + n_g] + 1.f);
#pragma unroll
        for (int mf = 0; mf < 4; ++mf) {
#pragma unroll
            for (int r = 0; r < 4; ++r) {
                int j_g = j0 + wm * 64 + mf * 16 + lg * 4 + r;
                float v = acc[mf][nf][r];
                if (resid) v += bf2f(Inb[(size_t)j_g * NN + n_g]);
                v *= scale;
                Outb[(size_t)j_g * NN + n_g] = f2bf(v);
            }
        }
    }
}

// ---------------- K5: out += Zcat @ W_dif[32:224] via MFMA; M=64 sites, N=32 d, K=192 ----------------
__global__ __launch_bounds__(256) void k_zmfma(const ushort* __restrict__ Z1,
                                               const ushort* __restrict__ Z2,
                                               const ushort* __restrict__ WdT_bf,
                                               float* __restrict__ out) {
    __shared__ __align__(16) ushort zT[64][200];    // [site][k<192]
    __shared__ __align__(16) ushort Wd_s[32][200];  // [d][k<192] = W_difT rows, k offset 32
    const size_t ZT = (size_t)BBATCH * NJ * NN;
    int t = threadIdx.x;
    int n0 = blockIdx.x * 64;
    int l = blockIdx.y;
    int b = blockIdx.z;
    for (int i = t; i < 768; i += 256) {
        int d = i / 24, c = i % 24;
        *(short8*)&Wd_s[d][c * 8] = *(const short8*)&WdT_bf[d * 224 + 32 + c * 8];
    }
    {
        int j = t >> 3, ch = t & 7;
#pragma unroll
        for (int c = 0; c < 6; ++c) {
            const ushort* Zp = ((c & 1) ? Z2 : Z1) + (size_t)(c >> 1) * ZT;
            short8 v = *(const short8*)&Zp[((size_t)b * NJ + l * 32 + j) * NN + n0 + ch * 8];
#pragma unroll
            for (int q = 0; q < 8; ++q) zT[ch * 8 + q][c * 32 + j] = (ushort)v[q];
        }
    }
    __syncthreads();
    int w = t >> 6, l6 = t & 63, lr = l6 & 15, lg = l6 >> 4;
    f32x4 acc[2];
    acc[0] = (f32x4){0.f, 0.f, 0.f, 0.f};
    acc[1] = (f32x4){0.f, 0.f, 0.f, 0.f};
#pragma unroll
    for (int kc = 0; kc < 6; ++kc) {
        short8 a = *(const short8*)&zT[w * 16 + lr][kc * 32 + lg * 8];
        short8 b0 = *(const short8*)&Wd_s[lr][kc * 32 + lg * 8];
        short8 b1 = *(const short8*)&Wd_s[16 + lr][kc * 32 + lg * 8];
        acc[0] = __builtin_amdgcn_mfma_f32_16x16x32_bf16(a, b0, acc[0], 0, 0, 0);
        acc[1] = __builtin_amdgcn_mfma_f32_16x16x32_bf16(a, b1, acc[1], 0, 0, 0);
    }
#pragma unroll
    for (int h = 0; h < 2; ++h) {
        int d = h * 16 + lr;
#pragma unroll
        for (int r = 0; r < 4; ++r) {
            int s = w * 16 + lg * 4 + r;
            size_t oi = (((size_t)b * LLEN + l) * NN + n0 + s) * 32 + d;
            out[oi] += acc[h][r];
        }
    }
}

extern "C" void kernel_launch(void* const* d_in, const int* in_sizes, int n_in,
                              void* d_out, int out_size, void* d_ws, size_t ws_size,
                              hipStream_t stream) {
    (void)in_sizes; (void)n_in; (void)out_size; (void)ws_size;
    const float* hist  = (const float*)d_in[0];
    const float* hs    = (const float*)d_in[1];
    const float* adj   = (const float*)d_in[2];
    const float* W_emb = (const float*)d_in[3];
    const float* b_emb = (const float*)d_in[4];
    const float* W_st  = (const float*)d_in[5];
    const float* b_st  = (const float*)d_in[6];
    const float* TiD   = (const float*)d_in[7];
    const float* DiW   = (const float*)d_in[8];
    const float* emb_u = (const float*)d_in[9];
    const float* emb_d = (const float*)d_in[10];
    const float* W_g1  = (const float*)d_in[11];
    const float* b_g1  = (const float*)d_in[12];
    const float* W_g2  = (const float*)d_in[13];
    const float* b_g2  = (const float*)d_in[14];
    const float* W_dif = (const float*)d_in[15];
    const float* b_dif = (const float*)d_in[16];
    float* out = (float*)d_out;

    // ws layout (bytes), total ~39.4 MB (ws_size ~268 MB per fill evidence)
    uint8_t* w8 = (uint8_t*)d_ws;
    ushort* adjF = (ushort*)w8;                      // 8 MB  adj bf16 [b][n][k]
    ushort* adjT = (ushort*)(w8 + 8388608);          // 8 MB  adj^T bf16 [b][n][k]
    ushort* S_bf = (ushort*)(w8 + 16777216);         // 2 MB
    ushort* XT   = (ushort*)(w8 + 18874368);         // 3 MB  [b][384][1024]
    ushort* Z1   = (ushort*)(w8 + 22020096);         // 9 MB  [s][b][384][1024]
    ushort* Z2   = (ushort*)(w8 + 31457280);         // 9 MB
    float*  rs   = (float*)(w8 + 40894464);          // 16 KB
    float*  cs   = (float*)(w8 + 40910848);          // 16 KB (contiguous with rs)
    float*  U1   = (float*)(w8 + 40927232);          // 256 KB
    float*  T1   = (float*)(w8 + 41189376);          // 72 KB
    float*  D1   = (float*)(w8 + 41263104);          // 1.8 KB
    ushort* WstT_bf = (ushort*)(w8 + 41264896);      // 6 KB  [32][96]
    ushort* WdT_bf  = (ushort*)(w8 + 41271040);      // 14 KB [32][224]

    hipMemsetAsync(rs, 0, 2 * BBATCH * NN * sizeof(float), stream);   // rs + cs
    k_adj_pre<<<dim3(16, 16, 4), 256, 0, stream>>>(adj, adjF, adjT, rs, cs);
    k_gate_pre<<<NN + TIDC + DIWC + 2, 64, 0, stream>>>(emb_u, emb_d, W_g1, b_g1, TiD, DiW,
                                                        W_st, W_dif, U1, T1, D1, WstT_bf, WdT_bf);
    k_static<<<NN, 256, 0, stream>>>(emb_u, emb_d, S_bf);
    k_xspa<<<dim3(16, 12, 4), 256, 0, stream>>>(hist, hs, W_emb, b_emb, b_st, U1, T1, D1,
                                                W_g2, b_g2, b_dif, WstT_bf, WdT_bf, XT, out);
    dim3 dgrid(3, 16, 12);
    k_diff3<<<dgrid, 256, 0, stream>>>(S_bf, adjF, adjT, rs, cs, XT, 0, Z1);
    k_diff3<<<dgrid, 256, 0, stream>>>(S_bf, adjF, adjT, rs, cs, Z1, 1, Z2);
    k_zmfma<<<dim3(16, 12, 4), 256, 0, stream>>>(Z1, Z2, WdT_bf, out);
}

// Round 10
// 196.005 us; speedup vs baseline: 3.2741x; 1.0792x over previous
//
#include <hip/hip_runtime.h>
#include <hip/hip_bf16.h>
#include <cstdint>

#define NN 1024
#define BBATCH 4
#define LLEN 12
#define NJ 384   // LLEN*32
#define TIDC 288
#define DIWC 7

typedef __attribute__((ext_vector_type(8))) short short8;
typedef __attribute__((ext_vector_type(4))) float f32x4;

typedef __attribute__((address_space(1))) const void* gas_ptr;
typedef __attribute__((address_space(3))) void* las_ptr;

__device__ inline ushort f2bf(float f) {
    unsigned u = __float_as_uint(f);
    u += 0x7FFFu + ((u >> 16) & 1u);
    return (ushort)(u >> 16);
}
__device__ inline float bf2f(ushort u) { return __uint_as_float(((unsigned)u) << 16); }

// ---------------- K_pre: merged adj-preprocess (bids 0..1023) + static support (1024..2047)
//                  + gate tables / weight transposes (2048..2378) ----------------
__global__ __launch_bounds__(256) void k_pre(const float* __restrict__ adj,
                                             ushort* __restrict__ adjF,
                                             ushort* __restrict__ adjT,
                                             float* __restrict__ rs,
                                             float* __restrict__ cs,
                                             const float* __restrict__ emb_u,
                                             const float* __restrict__ emb_d,
                                             ushort* __restrict__ S_bf,
                                             const float* __restrict__ W_g1,
                                             const float* __restrict__ b_g1,
                                             const float* __restrict__ TiD,
                                             const float* __restrict__ DiW,
                                             const float* __restrict__ W_st,
                                             const float* __restrict__ W_dif,
                                             float* __restrict__ U1,
                                             float* __restrict__ T1,
                                             float* __restrict__ D1,
                                             ushort* __restrict__ WstT_bf,
                                             ushort* __restrict__ WdT_bf) {
    __shared__ float smem[64 * 65];
    int bid = blockIdx.x;
    int t = threadIdx.x;
    if (bid < 1024) {
        // ---- adj preprocessing: adjF bf16, adjT bf16, row/col sums (atomic partials)
        float (*tile)[65] = (float(*)[65])smem;
        int b = bid >> 8;
        int r0 = ((bid >> 4) & 15) * 64, c0 = (bid & 15) * 64;
        int col = (t & 15) * 4, rb = t >> 4;
#pragma unroll
        for (int i = 0; i < 4; ++i) {
            int r = rb + i * 16;
            float4 v = *reinterpret_cast<const float4*>(&adj[((size_t)b * NN + r0 + r) * NN + c0 + col]);
            tile[r][col] = v.x; tile[r][col + 1] = v.y; tile[r][col + 2] = v.z; tile[r][col + 3] = v.w;
            unsigned lo = (unsigned)f2bf(v.x) | ((unsigned)f2bf(v.y) << 16);
            unsigned hi = (unsigned)f2bf(v.z) | ((unsigned)f2bf(v.w) << 16);
            *reinterpret_cast<uint2*>(&adjF[((size_t)b * NN + r0 + r) * NN + c0 + col]) = make_uint2(lo, hi);
        }
        __syncthreads();
        {
            int r4 = t >> 2, q4 = t & 3;
            float s1 = 0.f;
#pragma unroll
            for (int c = 0; c < 16; ++c) s1 += tile[r4][q4 * 16 + c];
            s1 += __shfl_xor(s1, 1, 64);
            s1 += __shfl_xor(s1, 2, 64);
            if (q4 == 0) atomicAdd(&rs[b * NN + r0 + r4], s1);
            float s2 = 0.f;
#pragma unroll
            for (int rr = 0; rr < 16; ++rr) s2 += tile[q4 * 16 + rr][r4];
            s2 += __shfl_xor(s2, 1, 64);
            s2 += __shfl_xor(s2, 2, 64);
            if (q4 == 0) atomicAdd(&cs[b * NN + c0 + r4], s2);
        }
        int j = t >> 2, ch = t & 3;
        short8 o0, o1;
#pragma unroll
        for (int q = 0; q < 8; ++q) o0[q] = (short)f2bf(tile[ch * 16 + q][j]);
#pragma unroll
        for (int q = 0; q < 8; ++q) o1[q] = (short)f2bf(tile[ch * 16 + 8 + q][j]);
        size_t orow = ((size_t)b * NN + c0 + j) * NN + r0 + ch * 16;
        *(short8*)&adjT[orow] = o0;
        *(short8*)&adjT[orow + 8] = o1;
    } else if (bid < 2048) {
        // ---- static support row: S = softmax(relu(emb_d @ emb_u^T), axis=1)
        int i = bid - 1024;
        float* drow = smem;
        float* red = smem + 32;
        if (t < 32) drow[t] = emb_d[i * 32 + t];
        __syncthreads();
        float v[4];
        float lsum = 0.f;
        for (int jj = 0; jj < 4; ++jj) {
            int j = jj * 256 + t;
            const float4* u4 = reinterpret_cast<const float4*>(emb_u + (size_t)j * 32);
            float acc = 0.f;
#pragma unroll
            for (int k4 = 0; k4 < 8; ++k4) {
                float4 u = u4[k4];
                acc += drow[k4 * 4 + 0] * u.x + drow[k4 * 4 + 1] * u.y +
                       drow[k4 * 4 + 2] * u.z + drow[k4 * 4 + 3] * u.w;
            }
            acc = fmaxf(acc, 0.f);
            v[jj] = __expf(acc);
            lsum += v[jj];
        }
        red[t] = lsum;
        __syncthreads();
        for (int s = 128; s > 0; s >>= 1) {
            if (t < s) red[t] += red[t + s];
            __syncthreads();
        }
        float inv = 1.f / red[0];
        for (int jj = 0; jj < 4; ++jj) S_bf[(size_t)i * NN + jj * 256 + t] = f2bf(v[jj] * inv);
    } else {
        // ---- gate tables: 4 conceptual 64-thread rows per block
        int r = (bid - 2048) * 4 + (t >> 6);
        int h = t & 63;
        if (r < NN) {
            float acc = b_g1[h];
            for (int i = 0; i < 32; ++i) acc = fmaf(emb_u[r * 32 + i], W_g1[(20 + i) * 64 + h], acc);
            for (int i = 0; i < 32; ++i) acc = fmaf(emb_d[r * 32 + i], W_g1[(52 + i) * 64 + h], acc);
            U1[r * 64 + h] = acc;
        } else if (r < NN + TIDC) {
            int tt = r - NN;
            float acc = 0.f;
            for (int i = 0; i < 10; ++i) acc = fmaf(TiD[tt * 10 + i], W_g1[i * 64 + h], acc);
            T1[tt * 64 + h] = acc;
        } else if (r < NN + TIDC + DIWC) {
            int dd = r - (NN + TIDC);
            float acc = 0.f;
            for (int i = 0; i < 10; ++i) acc = fmaf(DiW[dd * 10 + i], W_g1[(10 + i) * 64 + h], acc);
            D1[dd * 64 + h] = acc;
        } else if (r == NN + TIDC + DIWC) {
            for (int i = h; i < 32 * 96; i += 64) WstT_bf[i] = f2bf(W_st[(i % 96) * 32 + i / 96]);
        } else if (r == NN + TIDC + DIWC + 1) {
            for (int i = h; i < 32 * 224; i += 64) WdT_bf[i] = f2bf(W_dif[(i % 224) * 32 + i / 224]);
        }
    }
}

// ---------------- K3: fused H_st(MFMA) + H + gate + X_spa -> XT bf16 [b][j][n]  AND  out0(MFMA) ----------------
__global__ __launch_bounds__(256) void k_xspa(const float* __restrict__ hist,
                                              const float* __restrict__ hs,
                                              const float* __restrict__ W_emb,
                                              const float* __restrict__ b_emb,
                                              const float* __restrict__ b_st,
                                              const float* __restrict__ U1,
                                              const float* __restrict__ T1,
                                              const float* __restrict__ D1,
                                              const float* __restrict__ W_g2,
                                              const float* __restrict__ b_g2,
                                              const float* __restrict__ b_dif,
                                              const ushort* __restrict__ WstT_bf,
                                              const ushort* __restrict__ WdT_bf,
                                              ushort* __restrict__ XT,
                                              float* __restrict__ out) {
    __shared__ __align__(16) ushort hsm[64][104];    // [site][k<96], bf16
    __shared__ __align__(16) ushort Wst_s[32][104];  // [d][k<96]
    __shared__ __align__(16) ushort Hs_bf[64][40];   // [site][d<32]
    __shared__ __align__(16) ushort W0_s[32][40];    // [dout][j<32]
    __shared__ float gateL[64];
    __shared__ float histL[192];
    int t = threadIdx.x;
    int n0 = blockIdx.x * 64;
    int l = blockIdx.y;
    int b = blockIdx.z;
    for (int i = t; i < 384; i += 256) {
        int d = i / 12, c = i % 12;
        *(short8*)&Wst_s[d][c * 8] = *(const short8*)&WstT_bf[d * 96 + c * 8];
    }
    if (t < 128) {
        int d = t >> 2, c = t & 3;
        *(short8*)&W0_s[d][c * 8] = *(const short8*)&WdT_bf[d * 224 + c * 8];
    }
    if (t < 48)
        *(float4*)&histL[t * 4] =
            *(const float4*)&hist[(((size_t)b * LLEN + l) * NN + n0) * 3 + t * 4];
#pragma unroll
    for (int rr = 0; rr < 6; ++rr) {
        int i = t + 256 * rr;              // 0..1535 over (site, float4-chunk)
        int s = i / 24, c = i % 24;
        float4 v = *(const float4*)&hs[(((size_t)b * NN + n0 + s) * LLEN + l) * 96 + c * 4];
        ushort4 u;
        u.x = f2bf(v.x); u.y = f2bf(v.y); u.z = f2bf(v.z); u.w = f2bf(v.w);
        *(ushort4*)&hsm[s][c * 4] = u;
    }
    __syncthreads();
    // ---- gate phase: 64 sites x 4 lanes
    {
        int s = t >> 2, q = t & 3;
        int n = n0 + s;
        float x1 = histL[s * 3 + 1];
        float x2 = histL[s * 3 + 2] * (1.f / 7.f);
        int ti = (int)(x1 * 288.f); ti = ti < 0 ? 0 : (ti > 287 ? 287 : ti);
        int di = (int)(x2 * 7.f);   di = di < 0 ? 0 : (di > 6 ? 6 : di);
        const float* up = U1 + n * 64 + q * 16;
        const float* tp = T1 + ti * 64 + q * 16;
        const float* dp = D1 + di * 64 + q * 16;
        const float* wp = W_g2 + q * 16;
        float a = 0.f;
#pragma unroll
        for (int hh = 0; hh < 16; ++hh)
            a = fmaf(fmaxf(up[hh] + tp[hh] + dp[hh], 0.f), wp[hh], a);
        a += __shfl_xor(a, 1, 64);
        a += __shfl_xor(a, 2, 64);
        if (q == 0) gateL[s] = 1.f / (1.f + __expf(-(a + b_g2[0])));
    }
    // ---- MFMA H_st: M=64 sites (4 waves x 16), N=32 d, K=96
    int w = t >> 6, l6 = t & 63, lr = l6 & 15, lg = l6 >> 4;
    f32x4 hacc[2];
    hacc[0] = (f32x4){0.f, 0.f, 0.f, 0.f};
    hacc[1] = (f32x4){0.f, 0.f, 0.f, 0.f};
#pragma unroll
    for (int kc = 0; kc < 3; ++kc) {
        short8 a = *(const short8*)&hsm[w * 16 + lr][kc * 32 + lg * 8];
        short8 b0 = *(const short8*)&Wst_s[lr][kc * 32 + lg * 8];
        short8 b1 = *(const short8*)&Wst_s[16 + lr][kc * 32 + lg * 8];
        hacc[0] = __builtin_amdgcn_mfma_f32_16x16x32_bf16(a, b0, hacc[0], 0, 0, 0);
        hacc[1] = __builtin_amdgcn_mfma_f32_16x16x32_bf16(a, b1, hacc[1], 0, 0, 0);
    }
    // epilogue: H = relu(W_emb*x0 + b_emb + b_st + H_st) -> Hs_bf
#pragma unroll
    for (int h = 0; h < 2; ++h) {
        int d = h * 16 + lr;
        float we = W_emb[d];
        float bb = b_emb[d] + b_st[d];
#pragma unroll
        for (int r = 0; r < 4; ++r) {
            int s = w * 16 + lg * 4 + r;
            float v = fmaxf(fmaf(histL[s * 3], we, bb) + hacc[h][r], 0.f);
            Hs_bf[s][d] = f2bf(v);
        }
    }
    __syncthreads();
    // ---- MFMA out0: out = b_dif + gate * (H @ W_dif[0:32]), K=32
    f32x4 oacc[2];
    oacc[0] = (f32x4){0.f, 0.f, 0.f, 0.f};
    oacc[1] = (f32x4){0.f, 0.f, 0.f, 0.f};
    {
        short8 a = *(const short8*)&Hs_bf[w * 16 + lr][lg * 8];
        short8 b0 = *(const short8*)&W0_s[lr][lg * 8];
        short8 b1 = *(const short8*)&W0_s[16 + lr][lg * 8];
        oacc[0] = __builtin_amdgcn_mfma_f32_16x16x32_bf16(a, b0, oacc[0], 0, 0, 0);
        oacc[1] = __builtin_amdgcn_mfma_f32_16x16x32_bf16(a, b1, oacc[1], 0, 0, 0);
    }
#pragma unroll
    for (int h = 0; h < 2; ++h) {
        int d = h * 16 + lr;
        float bd = b_dif[d];
#pragma unroll
        for (int r = 0; r < 4; ++r) {
            int s = w * 16 + lg * 4 + r;
            out[(((size_t)b * LLEN + l) * NN + n0 + s) * 32 + d] = fmaf(gateL[s], oacc[h][r], bd);
        }
    }
    // ---- XT write
    {
        int dd = t >> 3, c = t & 7;
        short8 v;
#pragma unroll
        for (int i = 0; i < 8; ++i) {
            int s = c * 8 + i;
            v[i] = (short)f2bf(bf2f(Hs_bf[s][dd]) * gateL[s]);
        }
        *(short8*)&XT[((size_t)b * NJ + l * 32 + dd) * NN + n0 + c * 8] = v;
    }
}

// ---------------- K4: MFMA diffusion, BM=128 BN=64 BK=64, global_load_lds staging ----------
// LDS slot [row][c] holds global chunk c^(row&7) (pre-swizzled source); reads use the same XOR.
#define STAGE(buf, kt)                                                              \
    {                                                                               \
        const ushort* gA = pA + (size_t)(kt) * 64;                                  \
        const ushort* gW = pW + (size_t)(kt) * 64;                                  \
        _Pragma("unroll") for (int i = 0; i < 4; ++i)                               \
            __builtin_amdgcn_global_load_lds(                                        \
                (gas_ptr)(gA + aoff[i]),                                             \
                (las_ptr)&As[buf][(w * 32 + i * 8) * 64], 16, 0, 0);                \
        _Pragma("unroll") for (int i = 0; i < 2; ++i)                               \
            __builtin_amdgcn_global_load_lds(                                        \
                (gas_ptr)(gW + woff[i]),                                             \
                (las_ptr)&Ws[buf][(w * 16 + i * 8) * 64], 16, 0, 0);                \
    }
#define DIFF_COMPUTE(buf)                                              \
    {                                                                  \
        _Pragma("unroll") for (int kk = 0; kk < 2; ++kk) {             \
            short8 af[4], bff[2];                                      \
            _Pragma("unroll") for (int mf = 0; mf < 4; ++mf) {         \
                int row = wm * 64 + mf * 16 + lr;                      \
                af[mf] = *(const short8*)&As[buf][row * 64 + (((kk * 4 + lg) ^ (row & 7)) * 8)]; \
            }                                                          \
            _Pragma("unroll") for (int nf = 0; nf < 2; ++nf) {         \
                int row = wn * 32 + nf * 16 + lr;                      \
                bff[nf] = *(const short8*)&Ws[buf][row * 64 + (((kk * 4 + lg) ^ (row & 7)) * 8)]; \
            }                                                          \
            _Pragma("unroll") for (int mf = 0; mf < 4; ++mf) {         \
                acc[mf][0] = __builtin_amdgcn_mfma_f32_16x16x32_bf16(af[mf], bff[0], acc[mf][0], 0, 0, 0); \
                acc[mf][1] = __builtin_amdgcn_mfma_f32_16x16x32_bf16(af[mf], bff[1], acc[mf][1], 0, 0, 0); \
            }                                                          \
        }                                                              \
    }

__global__ __launch_bounds__(256) void k_diff3(const ushort* __restrict__ S_bf,
                                               const ushort* __restrict__ adjF,
                                               const ushort* __restrict__ adjT,
                                               const float* __restrict__ rs,
                                               const float* __restrict__ cs,
                                               const ushort* __restrict__ In0,
                                               int in_per_chain,
                                               ushort* __restrict__ Out0) {
    __shared__ __align__(16) ushort As[2][128 * 64];
    __shared__ __align__(16) ushort Ws[2][64 * 64];
    // bijective XCD swizzle over 576 blocks (72 per XCD); decode y-fastest within (x,z)
    int bid = blockIdx.x + 3 * blockIdx.y + 48 * blockIdx.z;
    int swz = (bid & 7) * 72 + (bid >> 3);
    int zz = swz / 48;
    int rem = swz % 48;
    int xx = rem >> 4, yy = rem & 15;
    int s = zz >> 2, b = zz & 3;
    int j0 = xx * 128;
    int n0 = yy * 64;
    const size_t ZT = (size_t)BBATCH * NJ * NN;
    const ushort* Wb = (s == 0) ? S_bf
                     : (s == 1) ? adjF + (size_t)b * NN * NN
                                : adjT + (size_t)b * NN * NN;
    const float* deg = (s == 0) ? nullptr : (s == 1 ? rs : cs);
    const ushort* Inb = In0 + (in_per_chain ? (size_t)s * ZT : 0) + (size_t)b * NJ * NN;
    ushort* Outb = Out0 + (size_t)s * ZT + (size_t)b * NJ * NN;

    int t = threadIdx.x;
    int w = t >> 6, wm = w >> 1, wn = w & 1;     // wave tile: 64j x 32n
    int l = t & 63, lr = l & 15, lg = l >> 4;
    // staging lane geometry: lane covers (row_local = l>>3, chunk = l&7), pre-swizzled source
    int rl = l >> 3, c8 = l & 7;
    size_t aoff[4], woff[2];
#pragma unroll
    for (int i = 0; i < 4; ++i) {
        int row = w * 32 + i * 8 + rl;
        aoff[i] = (size_t)row * NN + (size_t)((c8 ^ (row & 7)) * 8);
    }
#pragma unroll
    for (int i = 0; i < 2; ++i) {
        int row = w * 16 + i * 8 + rl;
        woff[i] = (size_t)row * NN + (size_t)((c8 ^ (row & 7)) * 8);
    }
    const ushort* pA = Inb + (size_t)j0 * NN;
    const ushort* pW = Wb + (size_t)n0 * NN;
    f32x4 acc[4][2];
#pragma unroll
    for (int i = 0; i < 4; ++i)
#pragma unroll
        for (int j = 0; j < 2; ++j) acc[i][j] = (f32x4){0.f, 0.f, 0.f, 0.f};

    STAGE(0, 0);
    __syncthreads();
    int cur = 0;
#pragma unroll 1
    for (int kt = 0; kt < 16; ++kt) {
        if (kt < 15) STAGE(cur ^ 1, kt + 1);   // issue next tile before compute
        DIFF_COMPUTE(cur);
        __syncthreads();                       // drains vmcnt(0): next tile landed
        cur ^= 1;
    }
    bool resid = (deg != nullptr);
#pragma unroll
    for (int nf = 0; nf < 2; ++nf) {
        int n_g = n0 + wn * 32 + nf * 16 + lr;
        float scale = 1.f;
        if (resid) scale = 1.f / (deg[b * NN + n_g] + 1.f);
#pragma unroll
        for (int mf = 0; mf < 4; ++mf) {
#pragma unroll
            for (int r = 0; r < 4; ++r) {
                int j_g = j0 + wm * 64 + mf * 16 + lg * 4 + r;
                float v = acc[mf][nf][r];
                if (resid) v += bf2f(Inb[(size_t)j_g * NN + n_g]);
                v *= scale;
                Outb[(size_t)j_g * NN + n_g] = f2bf(v);
            }
        }
    }
}

// ---------------- K5: out += Zcat @ W_dif[32:224] via MFMA; M=64 sites, N=32 d, K=192 ----------------
__global__ __launch_bounds__(256) void k_zmfma(const ushort* __restrict__ Z1,
                                               const ushort* __restrict__ Z2,
                                               const ushort* __restrict__ WdT_bf,
                                               float* __restrict__ out) {
    __shared__ __align__(16) ushort zT[64][200];    // [site][k<192]
    __shared__ __align__(16) ushort Wd_s[32][200];  // [d][k<192] = W_difT rows, k offset 32
    const size_t ZT = (size_t)BBATCH * NJ * NN;
    int t = threadIdx.x;
    int n0 = blockIdx.x * 64;
    int l = blockIdx.y;
    int b = blockIdx.z;
    for (int i = t; i < 768; i += 256) {
        int d = i / 24, c = i % 24;
        *(short8*)&Wd_s[d][c * 8] = *(const short8*)&WdT_bf[d * 224 + 32 + c * 8];
    }
    {
        int j = t >> 3, ch = t & 7;
#pragma unroll
        for (int c = 0; c < 6; ++c) {
            const ushort* Zp = ((c & 1) ? Z2 : Z1) + (size_t)(c >> 1) * ZT;
            short8 v = *(const short8*)&Zp[((size_t)b * NJ + l * 32 + j) * NN + n0 + ch * 8];
#pragma unroll
            for (int q = 0; q < 8; ++q) zT[ch * 8 + q][c * 32 + j] = (ushort)v[q];
        }
    }
    __syncthreads();
    int w = t >> 6, l6 = t & 63, lr = l6 & 15, lg = l6 >> 4;
    f32x4 acc[2];
    acc[0] = (f32x4){0.f, 0.f, 0.f, 0.f};
    acc[1] = (f32x4){0.f, 0.f, 0.f, 0.f};
#pragma unroll
    for (int kc = 0; kc < 6; ++kc) {
        short8 a = *(const short8*)&zT[w * 16 + lr][kc * 32 + lg * 8];
        short8 b0 = *(const short8*)&Wd_s[lr][kc * 32 + lg * 8];
        short8 b1 = *(const short8*)&Wd_s[16 + lr][kc * 32 + lg * 8];
        acc[0] = __builtin_amdgcn_mfma_f32_16x16x32_bf16(a, b0, acc[0], 0, 0, 0);
        acc[1] = __builtin_amdgcn_mfma_f32_16x16x32_bf16(a, b1, acc[1], 0, 0, 0);
    }
#pragma unroll
    for (int h = 0; h < 2; ++h) {
        int d = h * 16 + lr;
#pragma unroll
        for (int r = 0; r < 4; ++r) {
            int s = w * 16 + lg * 4 + r;
            size_t oi = (((size_t)b * LLEN + l) * NN + n0 + s) * 32 + d;
            out[oi] += acc[h][r];
        }
    }
}

extern "C" void kernel_launch(void* const* d_in, const int* in_sizes, int n_in,
                              void* d_out, int out_size, void* d_ws, size_t ws_size,
                              hipStream_t stream) {
    (void)in_sizes; (void)n_in; (void)out_size; (void)ws_size;
    const float* hist  = (const float*)d_in[0];
    const float* hs    = (const float*)d_in[1];
    const float* adj   = (const float*)d_in[2];
    const float* W_emb = (const float*)d_in[3];
    const float* b_emb = (const float*)d_in[4];
    const float* W_st  = (const float*)d_in[5];
    const float* b_st  = (const float*)d_in[6];
    const float* TiD   = (const float*)d_in[7];
    const float* DiW   = (const float*)d_in[8];
    const float* emb_u = (const float*)d_in[9];
    const float* emb_d = (const float*)d_in[10];
    const float* W_g1  = (const float*)d_in[11];
    const float* b_g1  = (const float*)d_in[12];
    const float* W_g2  = (const float*)d_in[13];
    const float* b_g2  = (const float*)d_in[14];
    const float* W_dif = (const float*)d_in[15];
    const float* b_dif = (const float*)d_in[16];
    float* out = (float*)d_out;

    // ws layout (bytes), total ~39.4 MB (ws_size ~268 MB per fill evidence)
    uint8_t* w8 = (uint8_t*)d_ws;
    ushort* adjF = (ushort*)w8;                      // 8 MB  adj bf16 [b][n][k]
    ushort* adjT = (ushort*)(w8 + 8388608);          // 8 MB  adj^T bf16 [b][n][k]
    ushort* S_bf = (ushort*)(w8 + 16777216);         // 2 MB
    ushort* XT   = (ushort*)(w8 + 18874368);         // 3 MB  [b][384][1024]
    ushort* Z1   = (ushort*)(w8 + 22020096);         // 9 MB  [s][b][384][1024]
    ushort* Z2   = (ushort*)(w8 + 31457280);         // 9 MB
    float*  rs   = (float*)(w8 + 40894464);          // 16 KB
    float*  cs   = (float*)(w8 + 40910848);          // 16 KB (contiguous with rs)
    float*  U1   = (float*)(w8 + 40927232);          // 256 KB
    float*  T1   = (float*)(w8 + 41189376);          // 72 KB
    float*  D1   = (float*)(w8 + 41263104);          // 1.8 KB
    ushort* WstT_bf = (ushort*)(w8 + 41264896);      // 6 KB  [32][96]
    ushort* WdT_bf  = (ushort*)(w8 + 41271040);      // 14 KB [32][224]

    hipMemsetAsync(rs, 0, 2 * BBATCH * NN * sizeof(float), stream);   // rs + cs
    k_pre<<<2379, 256, 0, stream>>>(adj, adjF, adjT, rs, cs, emb_u, emb_d, S_bf,
                                    W_g1, b_g1, TiD, DiW, W_st, W_dif,
                                    U1, T1, D1, WstT_bf, WdT_bf);
    k_xspa<<<dim3(16, 12, 4), 256, 0, stream>>>(hist, hs, W_emb, b_emb, b_st, U1, T1, D1,
                                                W_g2, b_g2, b_dif, WstT_bf, WdT_bf, XT, out);
    dim3 dgrid(3, 16, 12);
    k_diff3<<<dgrid, 256, 0, stream>>>(S_bf, adjF, adjT, rs, cs, XT, 0, Z1);
    k_diff3<<<dgrid, 256, 0, stream>>>(S_bf, adjF, adjT, rs, cs, Z1, 1, Z2);
    k_zmfma<<<dim3(16, 12, 4), 256, 0, stream>>>(Z1, Z2, WdT_bf, out);
}